// Round 5
// baseline (288.186 us; speedup 1.0000x reference)
//
#include <hip/hip_runtime.h>

#define B_DIM 8
#define T_DIM 2048
#define C_DIM 1024
#define H_DIM 128

typedef __attribute__((ext_vector_type(8))) short bf16x8;
typedef __attribute__((ext_vector_type(4))) float f32x4;

__device__ __forceinline__ short f2bf(float f) {
  union { float f; unsigned u; } v; v.f = f;
  unsigned u = v.u;
  unsigned r = (u + 0x7FFFu + ((u >> 16) & 1u)) >> 16;
  return (short)r;
}

// DPP rotate-reduce over the 16-lane row (n = lane&15), VALU-speed.
__device__ __forceinline__ float rowmax16(float x) {
  union { float f; int i; } a, t;
  a.f = x;
  t.i = __builtin_amdgcn_update_dpp(a.i, a.i, 0x128, 0xf, 0xf, false);  // ror:8
  a.f = fmaxf(a.f, t.f);
  t.i = __builtin_amdgcn_update_dpp(a.i, a.i, 0x124, 0xf, 0xf, false);  // ror:4
  a.f = fmaxf(a.f, t.f);
  t.i = __builtin_amdgcn_update_dpp(a.i, a.i, 0x122, 0xf, 0xf, false);  // ror:2
  a.f = fmaxf(a.f, t.f);
  t.i = __builtin_amdgcn_update_dpp(a.i, a.i, 0x121, 0xf, 0xf, false);  // ror:1
  a.f = fmaxf(a.f, t.f);
  return a.f;
}
__device__ __forceinline__ float rowsum16(float x) {
  union { float f; int i; } a, t;
  a.f = x;
  t.i = __builtin_amdgcn_update_dpp(a.i, a.i, 0x128, 0xf, 0xf, false);
  a.f += t.f;
  t.i = __builtin_amdgcn_update_dpp(a.i, a.i, 0x124, 0xf, 0xf, false);
  a.f += t.f;
  t.i = __builtin_amdgcn_update_dpp(a.i, a.i, 0x122, 0xf, 0xf, false);
  a.f += t.f;
  t.i = __builtin_amdgcn_update_dpp(a.i, a.i, 0x121, 0xf, 0xf, false);
  a.f += t.f;
  return a.f;
}

// ---------------------------------------------------------------------------
// Kernel 1: weight prep only (1.5 MB of work).  Wt[3][H=128][C=1024] bf16,
// 16B coalesced writes.  x conversion is fused into projf now.
// ---------------------------------------------------------------------------
#define NWE ((3 * C_DIM * H_DIM) / 8)       // 49152 items

__global__ __launch_bounds__(256) void wprep_kernel(
    const float* __restrict__ Wk, const float* __restrict__ Wq,
    const float* __restrict__ Wv, short* __restrict__ Wt) {
  int j = blockIdx.x * 256 + threadIdx.x;
  if (j >= NWE) return;
  int w = j >> 14;             // 16384 items per weight
  int r = j & 16383;
  int h = r >> 7;              // C/8 = 128 items per h
  int c0 = (r & 127) * 8;
  const float* W = (w == 0) ? Wk : ((w == 1) ? Wq : Wv);
  __attribute__((aligned(16))) short t[8];
#pragma unroll
  for (int i = 0; i < 8; i++) t[i] = f2bf(W[(size_t)(c0 + i) * H_DIM + h]);
  *(int4*)(Wt + (size_t)w * (C_DIM * H_DIM) + h * C_DIM + c0) = *(const int4*)t;
}

// ---------------------------------------------------------------------------
// Kernel 2: fused projection.  Reads x fp32 ONCE; one staged A-tile feeds all
// three weights (B = Wt rows 0..383, L2-resident).  Tile 64 rows x 384 cols,
// BK=32, 8 waves (wave = 32 rows x 96 cols = 2x6 16x16 tiles).  LDS double-
// buffered, pitch-40 rows (2-way-free bank pattern).  T14 pipeline: global
// loads for k+1 issued before compute on k; vmcnt drains post-compute.
// Outputs: Qb row-major; Kp/Vp MFMA-fragment-packed (as r4).
// ---------------------------------------------------------------------------
__global__ __launch_bounds__(512) void projf_kernel(
    const float* __restrict__ x, const short* __restrict__ Wt,
    short* __restrict__ Kp, short* __restrict__ Qb, short* __restrict__ Vp) {
  const int m0 = blockIdx.x * 64;
  __shared__ short As[2][64][40];     // 10 KB
  __shared__ short Bs[2][384][40];    // 60 KB
  const int tid  = threadIdx.x;
  const int lane = tid & 63;
  const int wv   = tid >> 6;
  const int n    = lane & 15;
  const int quad = lane >> 4;
  const int mh = wv >> 2;        // row half: rows mh*32 .. +32
  const int nq = wv & 3;         // col quarter: cols nq*96 .. +96

  // A staging: row = tid>>3 (0..63), 4 floats at (tid&7)*4
  const int ar = tid >> 3, ac = (tid & 7) * 4;
  // B staging: rows tid>>2, +128, +256; 8 shorts at (tid&3)*8
  const int br = tid >> 2, bc = (tid & 3) * 8;

  f32x4 acc[2][6];
#pragma unroll
  for (int i = 0; i < 2; i++)
#pragma unroll
    for (int j = 0; j < 6; j++) {
      f32x4 z = {0.f, 0.f, 0.f, 0.f};
      acc[i][j] = z;
    }

  float4 ax;
  int4 bx0, bx1, bx2;
  const float* xrow = x + (size_t)(m0 + ar) * C_DIM + ac;

  auto LOADG = [&](int k0) {
    ax  = *(const float4*)(xrow + k0);
    bx0 = *(const int4*)(Wt + (size_t)br * C_DIM + k0 + bc);
    bx1 = *(const int4*)(Wt + (size_t)(br + 128) * C_DIM + k0 + bc);
    bx2 = *(const int4*)(Wt + (size_t)(br + 256) * C_DIM + k0 + bc);
  };
  auto STORE = [&](int buf) {
    __attribute__((aligned(8))) short t4[4];
    t4[0] = f2bf(ax.x); t4[1] = f2bf(ax.y); t4[2] = f2bf(ax.z); t4[3] = f2bf(ax.w);
    *(int2*)&As[buf][ar][ac] = *(const int2*)t4;
    *(int4*)&Bs[buf][br][bc] = bx0;
    *(int4*)&Bs[buf][br + 128][bc] = bx1;
    *(int4*)&Bs[buf][br + 256][bc] = bx2;
  };
  auto COMPUTE = [&](int buf) {
    bf16x8 aF[2], bF[6];
#pragma unroll
    for (int mt = 0; mt < 2; mt++)
      aF[mt] = *(const bf16x8*)&As[buf][mh * 32 + mt * 16 + n][quad * 8];
#pragma unroll
    for (int nt = 0; nt < 6; nt++)
      bF[nt] = *(const bf16x8*)&Bs[buf][nq * 96 + nt * 16 + n][quad * 8];
#pragma unroll
    for (int mt = 0; mt < 2; mt++)
#pragma unroll
      for (int nt = 0; nt < 6; nt++)
        acc[mt][nt] = __builtin_amdgcn_mfma_f32_16x16x32_bf16(
            aF[mt], bF[nt], acc[mt][nt], 0, 0, 0);
  };

  LOADG(0);
  STORE(0);
  __syncthreads();
  for (int kk = 0; kk < 32; kk++) {
    if (kk < 31) LOADG((kk + 1) * 32);   // issue-early; vmcnt drains at barrier
    COMPUTE(kk & 1);
    __syncthreads();
    if (kk < 31) {
      STORE((kk + 1) & 1);               // write-late
      __syncthreads();
    }
  }

  // epilogue: C/D layout col = lane&15, row = quad*4 + reg
#pragma unroll
  for (int mt = 0; mt < 2; mt++) {
#pragma unroll
    for (int nt = 0; nt < 6; nt++) {
#pragma unroll
      for (int i = 0; i < 4; i++) {
        int row = m0 + mh * 32 + mt * 16 + quad * 4 + i;  // global token index
        int col = nq * 96 + nt * 16 + n;                  // 0..383
        short v = f2bf(acc[mt][nt][i]);
        int w = col >> 7;           // uniform per nt
        int c = col & 127;          // h index
        int bb = row >> 11;
        int t  = row & (T_DIM - 1);
        int tt = t >> 6;
        if (w == 0) {
          int rr = t & 63;
          int knt = rr >> 4, kn = rr & 15;
          int kc = c >> 5, kq = (c >> 3) & 3, kj = c & 7;
          Kp[(((size_t)(bb * 32 + tt) * 16 + knt * 4 + kc) * 512) +
             (kq * 16 + kn) * 8 + kj] = v;
        } else if (w == 1) {
          Qb[(size_t)row * H_DIM + c] = v;
        } else {
          int vkc = (t >> 5) & 1, vq = (t >> 3) & 3, vj = t & 7;
          int ht = c >> 4, vn = c & 15;
          Vp[(((size_t)(bb * 32 + tt) * 16 + ht * 2 + vkc) * 512) +
             (vq * 16 + vn) * 8 + vj] = v;
        }
      }
    }
  }
}

// ---------------------------------------------------------------------------
// Kernel 3: causal flash attention.  Barrier-free main loop (fragment-packed
// K/V, 1KB-segment loads, DPP softmax).  Now 8 waves / 8 kv-phases per
// 16-row q-tile (worst wave 4 tiles, was 8), log-tree 3-round merge,
// HEAVY-FIRST block order (high qt launches first -> no serial tail).
// ---------------------------------------------------------------------------
__global__ __launch_bounds__(512, 6) void attn_kernel(
    const short* __restrict__ Qb, const short* __restrict__ Kp,
    const short* __restrict__ Vp, float* __restrict__ out) {
  const int id = blockIdx.y * 128 + blockIdx.x;
  const int b  = id & 7;             // batch -> XCD spread
  const int qt = 127 - (id >> 3);    // heavy-first (LPT)
  const int q0 = qt * 16;
  const int tid  = threadIdx.x;
  const int lane = tid & 63;
  const int g    = tid >> 6;   // kv phase 0..7
  const int n    = lane & 15;
  const int quad = lane >> 4;

  __shared__ short Ps[8][16][72];    // per-wave P strips (18.4KB)
  __shared__ float Om[4][16][128];   // tree-merge O slots (32KB)
  __shared__ float Ml[4][16][2];

  const int ntiles = (qt >> 2) + 1;
  const float scale = 0.08838834764831845f;  // 1/sqrt(128)
  const int row0 = q0 + quad * 4;            // + reg i

  const short* Kbase = Kp + (size_t)b * 32 * 16 * 512;
  const short* Vbase = Vp + (size_t)b * 32 * 16 * 512;

  bf16x8 aQ[4];
  {
    const short* qrow = Qb + (size_t)(b * T_DIM + q0 + n) * H_DIM;
#pragma unroll
    for (int kc = 0; kc < 4; kc++)
      aQ[kc] = *(const bf16x8*)(qrow + kc * 32 + quad * 8);
  }

  f32x4 accO[8];
#pragma unroll
  for (int i = 0; i < 8; i++) {
    f32x4 z = {0.f, 0.f, 0.f, 0.f};
    accO[i] = z;
  }
  float mrow[4] = {-1e30f, -1e30f, -1e30f, -1e30f};
  float lrow[4] = {0.f, 0.f, 0.f, 0.f};

  for (int t = g; t < ntiles; t += 8) {
    const int j0 = t * 64;
    const short* Kt = Kbase + (size_t)t * 16 * 512 + lane * 8;
    const short* Vt = Vbase + (size_t)t * 16 * 512 + lane * 8;
    f32x4 accS[4];
#pragma unroll
    for (int nt = 0; nt < 4; nt++) {
      f32x4 z = {0.f, 0.f, 0.f, 0.f};
      accS[nt] = z;
    }
    bf16x8 fr[8];
    // ---- K batch 0 (nt 0,1) ----
#pragma unroll
    for (int nt = 0; nt < 2; nt++)
#pragma unroll
      for (int kc = 0; kc < 4; kc++)
        fr[nt * 4 + kc] = *(const bf16x8*)(Kt + (nt * 4 + kc) * 512);
    __builtin_amdgcn_sched_barrier(0);
#pragma unroll
    for (int nt = 0; nt < 2; nt++)
#pragma unroll
      for (int kc = 0; kc < 4; kc++)
        accS[nt] = __builtin_amdgcn_mfma_f32_16x16x32_bf16(
            aQ[kc], fr[nt * 4 + kc], accS[nt], 0, 0, 0);
    __builtin_amdgcn_sched_barrier(0);
    // ---- K batch 1 (nt 2,3) ----
#pragma unroll
    for (int nt = 0; nt < 2; nt++)
#pragma unroll
      for (int kc = 0; kc < 4; kc++)
        fr[nt * 4 + kc] = *(const bf16x8*)(Kt + ((nt + 2) * 4 + kc) * 512);
    __builtin_amdgcn_sched_barrier(0);
#pragma unroll
    for (int nt = 0; nt < 2; nt++)
#pragma unroll
      for (int kc = 0; kc < 4; kc++)
        accS[nt + 2] = __builtin_amdgcn_mfma_f32_16x16x32_bf16(
            aQ[kc], fr[nt * 4 + kc], accS[nt + 2], 0, 0, 0);
    __builtin_amdgcn_sched_barrier(0);

    // ---- scale + causal mask + row max (DPP) ----
    float mt4[4] = {-1e30f, -1e30f, -1e30f, -1e30f};
#pragma unroll
    for (int nt = 0; nt < 4; nt++) {
      int col = j0 + nt * 16 + n;
#pragma unroll
      for (int i = 0; i < 4; i++) {
        float s = accS[nt][i] * scale;
        s = (col > row0 + i) ? -1e30f : s;
        accS[nt][i] = s;
        mt4[i] = fmaxf(mt4[i], s);
      }
    }
#pragma unroll
    for (int i = 0; i < 4; i++) mt4[i] = rowmax16(mt4[i]);

    // ---- V batch 0 prefetch under softmax ----
    bf16x8 frv[8];
#pragma unroll
    for (int ht = 0; ht < 4; ht++)
#pragma unroll
      for (int kc = 0; kc < 2; kc++)
        frv[ht * 2 + kc] = *(const bf16x8*)(Vt + (ht * 2 + kc) * 512);
    __builtin_amdgcn_sched_barrier(0);

    // ---- softmax ----
    float alpha[4], rsum[4];
#pragma unroll
    for (int i = 0; i < 4; i++) {
      float mnew = fmaxf(mrow[i], mt4[i]);
      alpha[i] = __expf(mrow[i] - mnew);
      mrow[i] = mnew;
      rsum[i] = 0.f;
    }
#pragma unroll
    for (int nt = 0; nt < 4; nt++)
#pragma unroll
      for (int i = 0; i < 4; i++) {
        float p = __expf(accS[nt][i] - mrow[i]);
        rsum[i] += p;
        Ps[g][quad * 4 + i][nt * 16 + n] = f2bf(p);
      }
#pragma unroll
    for (int i = 0; i < 4; i++) {
      rsum[i] = rowsum16(rsum[i]);
      lrow[i] = lrow[i] * alpha[i] + rsum[i];
    }
#pragma unroll
    for (int ht = 0; ht < 8; ht++)
#pragma unroll
      for (int i = 0; i < 4; i++)
        accO[ht][i] *= alpha[i];

    asm volatile("s_waitcnt lgkmcnt(0)" ::: "memory");
    __builtin_amdgcn_sched_barrier(0);

    bf16x8 aP[2];
#pragma unroll
    for (int kc = 0; kc < 2; kc++)
      aP[kc] = *(const bf16x8*)&Ps[g][n][kc * 32 + quad * 8];

#pragma unroll
    for (int ht = 0; ht < 4; ht++)
#pragma unroll
      for (int kc = 0; kc < 2; kc++)
        accO[ht] = __builtin_amdgcn_mfma_f32_16x16x32_bf16(
            aP[kc], frv[ht * 2 + kc], accO[ht], 0, 0, 0);
    __builtin_amdgcn_sched_barrier(0);
#pragma unroll
    for (int ht = 0; ht < 4; ht++)
#pragma unroll
      for (int kc = 0; kc < 2; kc++)
        frv[ht * 2 + kc] = *(const bf16x8*)(Vt + ((ht + 4) * 2 + kc) * 512);
    __builtin_amdgcn_sched_barrier(0);
#pragma unroll
    for (int ht = 0; ht < 4; ht++)
#pragma unroll
      for (int kc = 0; kc < 2; kc++)
        accO[ht + 4] = __builtin_amdgcn_mfma_f32_16x16x32_bf16(
            aP[kc], frv[ht * 2 + kc], accO[ht + 4], 0, 0, 0);
  }

  // ---- log-tree merge of 8 kv-phase partials (3 rounds) ----
  auto MWRITE = [&](int s) {
#pragma unroll
    for (int i = 0; i < 4; i++) {
      int r = quad * 4 + i;
#pragma unroll
      for (int ht = 0; ht < 8; ht++)
        Om[s][r][ht * 16 + n] = accO[ht][i];
      if (n == 0) { Ml[s][r][0] = mrow[i]; Ml[s][r][1] = lrow[i]; }
    }
  };
  auto MCOMB = [&](int s) {
#pragma unroll
    for (int i = 0; i < 4; i++) {
      int r = quad * 4 + i;
      float m1 = Ml[s][r][0], l1 = Ml[s][r][1];
      float mnew = fmaxf(mrow[i], m1);
      float a0 = __expf(mrow[i] - mnew);
      float a1 = __expf(m1 - mnew);
      mrow[i] = mnew;
      lrow[i] = lrow[i] * a0 + l1 * a1;
#pragma unroll
      for (int ht = 0; ht < 8; ht++)
        accO[ht][i] = accO[ht][i] * a0 + Om[s][r][ht * 16 + n] * a1;
    }
  };

  __syncthreads();
  if (g & 1) MWRITE(g >> 1);
  __syncthreads();
  if (!(g & 1)) MCOMB(g >> 1);
  __syncthreads();
  if (!(g & 1) && (g & 2)) MWRITE(g >> 2);
  __syncthreads();
  if (!(g & 3)) MCOMB(g >> 2);
  __syncthreads();
  if (g == 4) MWRITE(0);
  __syncthreads();
  if (g == 0) {
#pragma unroll
    for (int i = 0; i < 4; i++) {
      int r = quad * 4 + i;
      float m1 = Ml[0][r][0], l1 = Ml[0][r][1];
      float mnew = fmaxf(mrow[i], m1);
      float a0 = __expf(mrow[i] - mnew);
      float a1 = __expf(m1 - mnew);
      float linv = 1.0f / (lrow[i] * a0 + l1 * a1);
      size_t base = (size_t)(b * T_DIM + q0 + r) * H_DIM;
#pragma unroll
      for (int ht = 0; ht < 8; ht++)
        out[base + ht * 16 + n] =
            (accO[ht][i] * a0 + Om[0][r][ht * 16 + n] * a1) * linv;
    }
  }
}

// ---------------------------------------------------------------------------
extern "C" void kernel_launch(void* const* d_in, const int* in_sizes, int n_in,
                              void* d_out, int out_size, void* d_ws, size_t ws_size,
                              hipStream_t stream) {
  (void)in_sizes; (void)n_in; (void)out_size; (void)ws_size;
  const float* x  = (const float*)d_in[0];
  const float* Wk = (const float*)d_in[1];
  const float* Wq = (const float*)d_in[2];
  const float* Wv = (const float*)d_in[3];
  float* out = (float*)d_out;

  char* ws = (char*)d_ws;
  short* Wt = (short*)ws;                               // 786,432 B
  short* Kp = (short*)(ws + 786432);                    // 4 MB (fragment-packed)
  short* Qb = (short*)(ws + 786432 + 4194304);          // 4 MB
  short* Vp = (short*)(ws + 786432 + 8388608);          // 4 MB (fragment-packed)

  wprep_kernel<<<dim3(192), dim3(256), 0, stream>>>(Wk, Wq, Wv, Wt);
  projf_kernel<<<dim3(256), dim3(512), 0, stream>>>(x, Wt, Kp, Qb, Vp);
  attn_kernel<<<dim3(128, 8), dim3(512), 0, stream>>>(Qb, Kp, Vp, out);
}

// Round 6
// 159.910 us; speedup vs baseline: 1.8022x; 1.8022x over previous
//
#include <hip/hip_runtime.h>

#define B_DIM 8
#define T_DIM 2048
#define C_DIM 1024
#define H_DIM 128

typedef __attribute__((ext_vector_type(8))) short bf16x8;
typedef __attribute__((ext_vector_type(4))) float f32x4;

__device__ __forceinline__ short f2bf(float f) {
  union { float f; unsigned u; } v; v.f = f;
  unsigned u = v.u;
  unsigned r = (u + 0x7FFFu + ((u >> 16) & 1u)) >> 16;
  return (short)r;
}

__device__ __forceinline__ void gload_lds16(const short* g, short* l) {
  __builtin_amdgcn_global_load_lds(
      (const __attribute__((address_space(1))) void*)g,
      (__attribute__((address_space(3))) void*)l, 16, 0, 0);
}

// DPP rotate-reduce over the 16-lane row (n = lane&15), VALU-speed.
__device__ __forceinline__ float rowmax16(float x) {
  union { float f; int i; } a, t;
  a.f = x;
  t.i = __builtin_amdgcn_update_dpp(a.i, a.i, 0x128, 0xf, 0xf, false);  // ror:8
  a.f = fmaxf(a.f, t.f);
  t.i = __builtin_amdgcn_update_dpp(a.i, a.i, 0x124, 0xf, 0xf, false);  // ror:4
  a.f = fmaxf(a.f, t.f);
  t.i = __builtin_amdgcn_update_dpp(a.i, a.i, 0x122, 0xf, 0xf, false);  // ror:2
  a.f = fmaxf(a.f, t.f);
  t.i = __builtin_amdgcn_update_dpp(a.i, a.i, 0x121, 0xf, 0xf, false);  // ror:1
  a.f = fmaxf(a.f, t.f);
  return a.f;
}
__device__ __forceinline__ float rowsum16(float x) {
  union { float f; int i; } a, t;
  a.f = x;
  t.i = __builtin_amdgcn_update_dpp(a.i, a.i, 0x128, 0xf, 0xf, false);
  a.f += t.f;
  t.i = __builtin_amdgcn_update_dpp(a.i, a.i, 0x124, 0xf, 0xf, false);
  a.f += t.f;
  t.i = __builtin_amdgcn_update_dpp(a.i, a.i, 0x122, 0xf, 0xf, false);
  a.f += t.f;
  t.i = __builtin_amdgcn_update_dpp(a.i, a.i, 0x121, 0xf, 0xf, false);
  a.f += t.f;
  return a.f;
}

// ---------------------------------------------------------------------------
// Kernel 1: weight prep (1.5 MB).  Wt[3][H=128][C=1024] bf16, 16B writes.
// ---------------------------------------------------------------------------
#define NWE ((3 * C_DIM * H_DIM) / 8)       // 49152 items

__global__ __launch_bounds__(256) void wprep_kernel(
    const float* __restrict__ Wk, const float* __restrict__ Wq,
    const float* __restrict__ Wv, short* __restrict__ Wt) {
  int j = blockIdx.x * 256 + threadIdx.x;
  if (j >= NWE) return;
  int w = j >> 14;             // 16384 items per weight
  int r = j & 16383;
  int h = r >> 7;              // C/8 = 128 items per h
  int c0 = (r & 127) * 8;
  const float* W = (w == 0) ? Wk : ((w == 1) ? Wq : Wv);
  __attribute__((aligned(16))) short t[8];
#pragma unroll
  for (int i = 0; i < 8; i++) t[i] = f2bf(W[(size_t)(c0 + i) * H_DIM + h]);
  *(int4*)(Wt + (size_t)w * (C_DIM * H_DIM) + h * C_DIM + c0) = *(const int4*)t;
}

// ---------------------------------------------------------------------------
// Kernel 2: fused projection v2.  Tile 64 rows x 384 cols (K|Q|V), BK=64,
// 512 thr (8 waves, wave = 32 rows x 96 cols = 2x6 frags).  16 K-iters,
// m97 2-barrier loop.  B staged via gload_lds from bf16 Wt with BOTH-SIDES
// XOR swizzle (pre-swizzled global source granule, ^((row&7)<<4) on read)
// -> conflict-free ds_read_b128.  A reg-staged fp32->bf16 with T14
// issue-early/write-late (loads for iter t+1 in flight during compute on t).
// Outputs: Qb row-major; Kp/Vp MFMA-fragment-packed (epilogue = r5 verified).
// ---------------------------------------------------------------------------
__global__ __launch_bounds__(512, 2) void projf_kernel(
    const float* __restrict__ x, const short* __restrict__ Wt,
    short* __restrict__ Kp, short* __restrict__ Qb, short* __restrict__ Vp) {
  const int m0 = blockIdx.x * 64;
  __shared__ short As[64][72];      // padded (pitch 144B: (n+quad)%8 banks, free)
  __shared__ short Bs[384 * 64];    // linear for gload_lds; storage XOR-swizzled
  const int tid  = threadIdx.x;
  const int lane = tid & 63;
  const int wv   = tid >> 6;
  const int n    = lane & 15;
  const int quad = lane >> 4;
  const int mh = wv >> 2;        // 0..1: rows mh*32 .. +32
  const int nq = wv & 3;         // 0..3: cols nq*96 .. +96

  // A staging: row = tid>>3 (0..63), 8 floats at (tid&7)*8
  const int ar = tid >> 3, ac = (tid & 7) * 8;
  const float* xrow = x + (size_t)(m0 + ar) * C_DIM + ac;
  // B staging source swizzle: granule (lane&7) ^ (lane>>3) of the 8x128B chunk
  const int brl = lane >> 3;                    // row within chunk
  const int bce = 8 * ((lane & 7) ^ brl);       // pre-swizzled elem offset

  f32x4 acc[2][6];
#pragma unroll
  for (int i = 0; i < 2; i++)
#pragma unroll
    for (int j = 0; j < 6; j++) {
      f32x4 z = {0.f, 0.f, 0.f, 0.f};
      acc[i][j] = z;
    }

  float4 ax0, ax1;
  auto LOADA = [&](int k0) {
    ax0 = *(const float4*)(xrow + k0);
    ax1 = *(const float4*)(xrow + k0 + 4);
  };
  auto STOREA = [&]() {
    __attribute__((aligned(16))) short t8[8];
    t8[0] = f2bf(ax0.x); t8[1] = f2bf(ax0.y); t8[2] = f2bf(ax0.z); t8[3] = f2bf(ax0.w);
    t8[4] = f2bf(ax1.x); t8[5] = f2bf(ax1.y); t8[6] = f2bf(ax1.z); t8[7] = f2bf(ax1.w);
    *(int4*)&As[ar][ac] = *(const int4*)t8;
  };

  LOADA(0);
  for (int it = 0; it < 16; it++) {
    const int k0 = it * 64;
    __syncthreads();                 // (1) previous compute done, LDS reusable
    // B: 48 chunks of 1KB (8 rows x 128B), 6 per wave, wave-uniform dest
#pragma unroll
    for (int h = 0; h < 6; h++) {
      int c = wv * 6 + h;
      gload_lds16(Wt + (size_t)(c * 8 + brl) * C_DIM + k0 + bce, &Bs[c * 512]);
    }
    STOREA();                        // convert + write A loaded last iter
    if (it < 15) LOADA(k0 + 64);     // issue next A; drained by barrier (2)
    __syncthreads();                 // (2) vmcnt+lgkm drain (m97 semantics)

#pragma unroll
    for (int kk = 0; kk < 2; kk++) {
      bf16x8 aF[2], bF[6];
#pragma unroll
      for (int mt = 0; mt < 2; mt++)
        aF[mt] = *(const bf16x8*)&As[mh * 32 + mt * 16 + n][kk * 32 + quad * 8];
#pragma unroll
      for (int nt = 0; nt < 6; nt++) {
        int row = nq * 96 + nt * 16 + n;
        int off = (kk * 64 + quad * 16) ^ ((row & 7) << 4);   // bytes
        bF[nt] = *(const bf16x8*)((const char*)&Bs[row * 64] + off);
      }
#pragma unroll
      for (int mt = 0; mt < 2; mt++)
#pragma unroll
        for (int nt = 0; nt < 6; nt++)
          acc[mt][nt] = __builtin_amdgcn_mfma_f32_16x16x32_bf16(
              aF[mt], bF[nt], acc[mt][nt], 0, 0, 0);
    }
  }

  // epilogue (verified in r5): C/D layout col = lane&15, row = quad*4 + reg
#pragma unroll
  for (int mt = 0; mt < 2; mt++) {
#pragma unroll
    for (int nt = 0; nt < 6; nt++) {
#pragma unroll
      for (int i = 0; i < 4; i++) {
        int row = m0 + mh * 32 + mt * 16 + quad * 4 + i;  // global token index
        int col = nq * 96 + nt * 16 + n;                  // 0..383
        short v = f2bf(acc[mt][nt][i]);
        int w = col >> 7;
        int c = col & 127;          // h index
        int bb = row >> 11;
        int t  = row & (T_DIM - 1);
        int tt = t >> 6;
        if (w == 0) {
          int rr = t & 63;
          int knt = rr >> 4, kn = rr & 15;
          int kc = c >> 5, kq = (c >> 3) & 3, kj = c & 7;
          Kp[(((size_t)(bb * 32 + tt) * 16 + knt * 4 + kc) * 512) +
             (kq * 16 + kn) * 8 + kj] = v;
        } else if (w == 1) {
          Qb[(size_t)row * H_DIM + c] = v;
        } else {
          int vkc = (t >> 5) & 1, vq = (t >> 3) & 3, vj = t & 7;
          int ht = c >> 4, vn = c & 15;
          Vp[(((size_t)(bb * 32 + tt) * 16 + ht * 2 + vkc) * 512) +
             (vq * 16 + vn) * 8 + vj] = v;
        }
      }
    }
  }
}

// ---------------------------------------------------------------------------
// Kernel 3: causal flash attention — r4-proven structure (47us) with the
// VGPR clamp REMOVED (r5's (512,6) forced 40 VGPR -> 560MB spill traffic).
// (256,2): cap 256, expected use ~190, zero spills, 2 waves/SIMD.
// Single 16-frag K batch (one latency exposure).  LPT heavy-first qt order.
// Barrier-free main loop; fragment-packed K/V 1KB-segment loads; DPP softmax.
// ---------------------------------------------------------------------------
__global__ __launch_bounds__(256, 2) void attn_kernel(
    const short* __restrict__ Qb, const short* __restrict__ Kp,
    const short* __restrict__ Vp, float* __restrict__ out) {
  const int id = blockIdx.y * 128 + blockIdx.x;
  const int b  = id & 7;             // batch -> XCD spread
  const int qt = 127 - (id >> 3);    // heavy-first (LPT)
  const int q0 = qt * 16;
  const int tid  = threadIdx.x;
  const int lane = tid & 63;
  const int g    = tid >> 6;   // kv phase 0..3
  const int n    = lane & 15;
  const int quad = lane >> 4;

  __shared__ short Ps[4][16][72];   // per-wave P strips (9.2KB)
  __shared__ float Om[16][128];     // merge buffer (8KB)
  __shared__ float Ml[16][2];

  const int ntiles = (qt >> 2) + 1;
  const float scale = 0.08838834764831845f;  // 1/sqrt(128)
  const int row0 = q0 + quad * 4;            // + reg i

  const short* Kbase = Kp + (size_t)b * 32 * 16 * 512;
  const short* Vbase = Vp + (size_t)b * 32 * 16 * 512;

  // Q A-frags (same for all 4 waves)
  bf16x8 aQ[4];
  {
    const short* qrow = Qb + (size_t)(b * T_DIM + q0 + n) * H_DIM;
#pragma unroll
    for (int kc = 0; kc < 4; kc++)
      aQ[kc] = *(const bf16x8*)(qrow + kc * 32 + quad * 8);
  }

  f32x4 accO[8];
#pragma unroll
  for (int i = 0; i < 8; i++) {
    f32x4 z = {0.f, 0.f, 0.f, 0.f};
    accO[i] = z;
  }
  float mrow[4] = {-1e30f, -1e30f, -1e30f, -1e30f};
  float lrow[4] = {0.f, 0.f, 0.f, 0.f};

  for (int t = g; t < ntiles; t += 4) {
    const int j0 = t * 64;
    const short* Kt = Kbase + (size_t)t * 16 * 512 + lane * 8;
    const short* Vt = Vbase + (size_t)t * 16 * 512 + lane * 8;
    f32x4 accS[4];
#pragma unroll
    for (int nt = 0; nt < 4; nt++) {
      f32x4 z = {0.f, 0.f, 0.f, 0.f};
      accS[nt] = z;
    }
    // ---- K: all 16 coalesced 1KB loads in flight, then 16 MFMAs ----
    bf16x8 fr[16];
#pragma unroll
    for (int nt = 0; nt < 4; nt++)
#pragma unroll
      for (int kc = 0; kc < 4; kc++)
        fr[nt * 4 + kc] = *(const bf16x8*)(Kt + (nt * 4 + kc) * 512);
    __builtin_amdgcn_sched_barrier(0);
#pragma unroll
    for (int nt = 0; nt < 4; nt++)
#pragma unroll
      for (int kc = 0; kc < 4; kc++)
        accS[nt] = __builtin_amdgcn_mfma_f32_16x16x32_bf16(
            aQ[kc], fr[nt * 4 + kc], accS[nt], 0, 0, 0);
    __builtin_amdgcn_sched_barrier(0);

    // ---- scale + causal mask + row max (DPP) ----
    float mt4[4] = {-1e30f, -1e30f, -1e30f, -1e30f};
#pragma unroll
    for (int nt = 0; nt < 4; nt++) {
      int col = j0 + nt * 16 + n;
#pragma unroll
      for (int i = 0; i < 4; i++) {
        float s = accS[nt][i] * scale;
        s = (col > row0 + i) ? -1e30f : s;
        accS[nt][i] = s;
        mt4[i] = fmaxf(mt4[i], s);
      }
    }
#pragma unroll
    for (int i = 0; i < 4; i++) mt4[i] = rowmax16(mt4[i]);

    // ---- V batch 0 prefetch under softmax ----
    bf16x8 frv[8];
#pragma unroll
    for (int ht = 0; ht < 4; ht++)
#pragma unroll
      for (int kc = 0; kc < 2; kc++)
        frv[ht * 2 + kc] = *(const bf16x8*)(Vt + (ht * 2 + kc) * 512);
    __builtin_amdgcn_sched_barrier(0);

    // ---- softmax ----
    float alpha[4], rsum[4];
#pragma unroll
    for (int i = 0; i < 4; i++) {
      float mnew = fmaxf(mrow[i], mt4[i]);
      alpha[i] = __expf(mrow[i] - mnew);
      mrow[i] = mnew;
      rsum[i] = 0.f;
    }
#pragma unroll
    for (int nt = 0; nt < 4; nt++)
#pragma unroll
      for (int i = 0; i < 4; i++) {
        float p = __expf(accS[nt][i] - mrow[i]);
        rsum[i] += p;
        Ps[g][quad * 4 + i][nt * 16 + n] = f2bf(p);
      }
#pragma unroll
    for (int i = 0; i < 4; i++) {
      rsum[i] = rowsum16(rsum[i]);
      lrow[i] = lrow[i] * alpha[i] + rsum[i];
    }
#pragma unroll
    for (int ht = 0; ht < 8; ht++)
#pragma unroll
      for (int i = 0; i < 4; i++)
        accO[ht][i] *= alpha[i];

    // P strip written+read by the SAME wave: lgkmcnt wait suffices (rule 18)
    asm volatile("s_waitcnt lgkmcnt(0)" ::: "memory");
    __builtin_amdgcn_sched_barrier(0);

    bf16x8 aP[2];
#pragma unroll
    for (int kc = 0; kc < 2; kc++)
      aP[kc] = *(const bf16x8*)&Ps[g][n][kc * 32 + quad * 8];

    // ---- PV batch 0 (ht 0..3) ----
#pragma unroll
    for (int ht = 0; ht < 4; ht++)
#pragma unroll
      for (int kc = 0; kc < 2; kc++)
        accO[ht] = __builtin_amdgcn_mfma_f32_16x16x32_bf16(
            aP[kc], frv[ht * 2 + kc], accO[ht], 0, 0, 0);
    __builtin_amdgcn_sched_barrier(0);
    // ---- V batch 1 (ht 4..7) ----
#pragma unroll
    for (int ht = 0; ht < 4; ht++)
#pragma unroll
      for (int kc = 0; kc < 2; kc++)
        frv[ht * 2 + kc] = *(const bf16x8*)(Vt + ((ht + 4) * 2 + kc) * 512);
    __builtin_amdgcn_sched_barrier(0);
#pragma unroll
    for (int ht = 0; ht < 4; ht++)
#pragma unroll
      for (int kc = 0; kc < 2; kc++)
        accO[ht + 4] = __builtin_amdgcn_mfma_f32_16x16x32_bf16(
            aP[kc], frv[ht * 2 + kc], accO[ht + 4], 0, 0, 0);
  }

  // ---- merge the 4 kv-phase partials ----
  __syncthreads();
  if (g == 0) {
#pragma unroll
    for (int i = 0; i < 4; i++) {
      int r = quad * 4 + i;
#pragma unroll
      for (int ht = 0; ht < 8; ht++)
        Om[r][ht * 16 + n] = accO[ht][i];
      if (n == 0) { Ml[r][0] = mrow[i]; Ml[r][1] = lrow[i]; }
    }
  }
#pragma unroll
  for (int gg = 1; gg < 4; gg++) {
    __syncthreads();
    if (g == gg) {
#pragma unroll
      for (int i = 0; i < 4; i++) {
        int r = quad * 4 + i;
        float m1 = Ml[r][0], l1 = Ml[r][1];
        float mnew = fmaxf(mrow[i], m1);
        float a0 = __expf(mrow[i] - mnew);   // 0 when this phase had no tiles
        float a1 = __expf(m1 - mnew);
        float lnew = lrow[i] * a0 + l1 * a1;
        if (gg < 3) {
          if (n == 0) { Ml[r][0] = mnew; Ml[r][1] = lnew; }
#pragma unroll
          for (int ht = 0; ht < 8; ht++)
            Om[r][ht * 16 + n] = accO[ht][i] * a0 + Om[r][ht * 16 + n] * a1;
        } else {
          float linv = 1.0f / lnew;
          size_t base = (size_t)(b * T_DIM + q0 + r) * H_DIM;
#pragma unroll
          for (int ht = 0; ht < 8; ht++)
            out[base + ht * 16 + n] =
                (accO[ht][i] * a0 + Om[r][ht * 16 + n] * a1) * linv;
        }
      }
    }
  }
}

// ---------------------------------------------------------------------------
extern "C" void kernel_launch(void* const* d_in, const int* in_sizes, int n_in,
                              void* d_out, int out_size, void* d_ws, size_t ws_size,
                              hipStream_t stream) {
  (void)in_sizes; (void)n_in; (void)out_size; (void)ws_size;
  const float* x  = (const float*)d_in[0];
  const float* Wk = (const float*)d_in[1];
  const float* Wq = (const float*)d_in[2];
  const float* Wv = (const float*)d_in[3];
  float* out = (float*)d_out;

  char* ws = (char*)d_ws;
  short* Wt = (short*)ws;                               // 786,432 B
  short* Kp = (short*)(ws + 786432);                    // 4 MB (fragment-packed)
  short* Qb = (short*)(ws + 786432 + 4194304);          // 4 MB
  short* Vp = (short*)(ws + 786432 + 8388608);          // 4 MB (fragment-packed)

  wprep_kernel<<<dim3(192), dim3(256), 0, stream>>>(Wk, Wq, Wv, Wt);
  projf_kernel<<<dim3(256), dim3(512), 0, stream>>>(x, Wt, Kp, Qb, Vp);
  attn_kernel<<<dim3(128, 8), dim3(256), 0, stream>>>(Qb, Kp, Vp, out);
}

// Round 7
// 158.089 us; speedup vs baseline: 1.8229x; 1.0115x over previous
//
#include <hip/hip_runtime.h>

#define B_DIM 8
#define T_DIM 2048
#define C_DIM 1024
#define H_DIM 128

typedef __attribute__((ext_vector_type(8))) short bf16x8;
typedef __attribute__((ext_vector_type(4))) float f32x4;

__device__ __forceinline__ short f2bf(float f) {
  union { float f; unsigned u; } v; v.f = f;
  unsigned u = v.u;
  unsigned r = (u + 0x7FFFu + ((u >> 16) & 1u)) >> 16;
  return (short)r;
}

__device__ __forceinline__ void gload_lds16(const short* g, short* l) {
  __builtin_amdgcn_global_load_lds(
      (const __attribute__((address_space(1))) void*)g,
      (__attribute__((address_space(3))) void*)l, 16, 0, 0);
}

// DPP rotate-reduce over the 16-lane row (n = lane&15), VALU-speed.
__device__ __forceinline__ float rowmax16(float x) {
  union { float f; int i; } a, t;
  a.f = x;
  t.i = __builtin_amdgcn_update_dpp(a.i, a.i, 0x128, 0xf, 0xf, false);  // ror:8
  a.f = fmaxf(a.f, t.f);
  t.i = __builtin_amdgcn_update_dpp(a.i, a.i, 0x124, 0xf, 0xf, false);  // ror:4
  a.f = fmaxf(a.f, t.f);
  t.i = __builtin_amdgcn_update_dpp(a.i, a.i, 0x122, 0xf, 0xf, false);  // ror:2
  a.f = fmaxf(a.f, t.f);
  t.i = __builtin_amdgcn_update_dpp(a.i, a.i, 0x121, 0xf, 0xf, false);  // ror:1
  a.f = fmaxf(a.f, t.f);
  return a.f;
}
__device__ __forceinline__ float rowsum16(float x) {
  union { float f; int i; } a, t;
  a.f = x;
  t.i = __builtin_amdgcn_update_dpp(a.i, a.i, 0x128, 0xf, 0xf, false);
  a.f += t.f;
  t.i = __builtin_amdgcn_update_dpp(a.i, a.i, 0x124, 0xf, 0xf, false);
  a.f += t.f;
  t.i = __builtin_amdgcn_update_dpp(a.i, a.i, 0x122, 0xf, 0xf, false);
  a.f += t.f;
  t.i = __builtin_amdgcn_update_dpp(a.i, a.i, 0x121, 0xf, 0xf, false);
  a.f += t.f;
  return a.f;
}

// ---------------------------------------------------------------------------
// Kernel 1: weight prep (1.5 MB).  Wt[3][H=128][C=1024] bf16, 16B writes.
// ---------------------------------------------------------------------------
#define NWE ((3 * C_DIM * H_DIM) / 8)       // 49152 items

__global__ __launch_bounds__(256) void wprep_kernel(
    const float* __restrict__ Wk, const float* __restrict__ Wq,
    const float* __restrict__ Wv, short* __restrict__ Wt) {
  int j = blockIdx.x * 256 + threadIdx.x;
  if (j >= NWE) return;
  int w = j >> 14;             // 16384 items per weight
  int r = j & 16383;
  int h = r >> 7;              // C/8 = 128 items per h
  int c0 = (r & 127) * 8;
  const float* W = (w == 0) ? Wk : ((w == 1) ? Wq : Wv);
  __attribute__((aligned(16))) short t[8];
#pragma unroll
  for (int i = 0; i < 8; i++) t[i] = f2bf(W[(size_t)(c0 + i) * H_DIM + h]);
  *(int4*)(Wt + (size_t)w * (C_DIM * H_DIM) + h * C_DIM + c0) = *(const int4*)t;
}

// ---------------------------------------------------------------------------
// Kernel 2: fused projection v3 = r6 structure + T3/T4 counted-vmcnt
// pipeline.  r6's __syncthreads drained vmcnt(0) every iter (exposed ~900cy
// HBM A-latency + B L2 latency at 1 block/CU -> 46us, nothing >10% busy).
// Now: double-buffered As/Bs (114KB LDS), raw s_barrier, and per-iter
// staging issues A(t+2)+B(t+2) then waits vmcnt(7) -- exactly drains
// B(t+1)x6+A(t+1) consumed next iter while keeping 7 loads in flight.
// Staging geometry, XOR swizzle, epilogue identical to r6 (verified).
// ---------------------------------------------------------------------------
__global__ __launch_bounds__(512, 2) void projf_kernel(
    const float* __restrict__ x, const short* __restrict__ Wt,
    short* __restrict__ Kp, short* __restrict__ Qb, short* __restrict__ Vp) {
  const int m0 = blockIdx.x * 64;
  __shared__ short As[2][64][72];     // 18.4 KB (pitch 144B, 2-way free)
  __shared__ short Bs[2][384 * 64];   // 96 KB, linear; storage XOR-swizzled
  const int tid  = threadIdx.x;
  const int lane = tid & 63;
  const int wv   = tid >> 6;
  const int n    = lane & 15;
  const int quad = lane >> 4;
  const int mh = wv >> 2;        // 0..1: rows mh*32 .. +32
  const int nq = wv & 3;         // 0..3: cols nq*96 .. +96

  const int ar = tid >> 3, ac = (tid & 7) * 8;
  const float* xrow = x + (size_t)(m0 + ar) * C_DIM + ac;
  const int brl = lane >> 3;                    // row within 8x128B chunk
  const int bce = 8 * ((lane & 7) ^ brl);       // pre-swizzled elem offset

  f32x4 acc[2][6];
#pragma unroll
  for (int i = 0; i < 2; i++)
#pragma unroll
    for (int j = 0; j < 6; j++) {
      f32x4 z = {0.f, 0.f, 0.f, 0.f};
      acc[i][j] = z;
    }

  float4 a0x, a0y, a1x, a1y;   // two A reg sets (static indexing, rule 20)

  auto LOADA = [&](int k0, float4& u, float4& v) {
    u = *(const float4*)(xrow + k0);
    v = *(const float4*)(xrow + k0 + 4);
  };
  auto STOREA = [&](int buf, const float4& u, const float4& v) {
    __attribute__((aligned(16))) short t8[8];
    t8[0] = f2bf(u.x); t8[1] = f2bf(u.y); t8[2] = f2bf(u.z); t8[3] = f2bf(u.w);
    t8[4] = f2bf(v.x); t8[5] = f2bf(v.y); t8[6] = f2bf(v.z); t8[7] = f2bf(v.w);
    *(int4*)&As[buf][ar][ac] = *(const int4*)t8;
  };
  auto ISSUEB = [&](int buf, int k0) {
#pragma unroll
    for (int h = 0; h < 6; h++) {
      int c = wv * 6 + h;
      gload_lds16(Wt + (size_t)(c * 8 + brl) * C_DIM + k0 + bce,
                  &Bs[buf][c * 512]);
    }
  };
  auto COMPUTE = [&](int buf) {
#pragma unroll
    for (int kk = 0; kk < 2; kk++) {
      bf16x8 aF[2], bF[6];
#pragma unroll
      for (int mt = 0; mt < 2; mt++)
        aF[mt] = *(const bf16x8*)&As[buf][mh * 32 + mt * 16 + n][kk * 32 + quad * 8];
#pragma unroll
      for (int nt = 0; nt < 6; nt++) {
        int row = nq * 96 + nt * 16 + n;
        int off = (kk * 64 + quad * 16) ^ ((row & 7) << 4);   // bytes
        bF[nt] = *(const bf16x8*)((const char*)&Bs[buf][row * 64] + off);
      }
#pragma unroll
      for (int mt = 0; mt < 2; mt++)
#pragma unroll
        for (int nt = 0; nt < 6; nt++)
          acc[mt][nt] = __builtin_amdgcn_mfma_f32_16x16x32_bf16(
              aF[mt], bF[nt], acc[mt][nt], 0, 0, 0);
    }
  };

  // prologue: establish invariant {A(t+1), B(t+1)x6} = 7 outstanding
  LOADA(0, a0x, a0y);
  ISSUEB(0, 0);
  STOREA(0, a0x, a0y);             // compiler auto-waits vmcnt(6) for A(0)
  LOADA(64, a1x, a1y);
  ISSUEB(1, 64);
  asm volatile("s_waitcnt vmcnt(7)" ::: "memory");   // B(0) in LDS
  asm volatile("s_waitcnt lgkmcnt(0)" ::: "memory"); // As(0) written
  __builtin_amdgcn_sched_barrier(0);
  __builtin_amdgcn_s_barrier();
  __builtin_amdgcn_sched_barrier(0);

#pragma unroll
  for (int t = 0; t < 16; ++t) {
    COMPUTE(t & 1);
    if (t < 15) {
      __builtin_amdgcn_s_barrier();        // all waves done reading buf[t&1]
      __builtin_amdgcn_sched_barrier(0);
      if ((t & 1) == 0) STOREA(1, a1x, a1y);   // As[(t+1)&1], set loaded @t-1
      else              STOREA(0, a0x, a0y);
      if (t + 2 < 16) {
        if ((t & 1) == 0) LOADA((t + 2) * 64, a0x, a0y);
        else              LOADA((t + 2) * 64, a1x, a1y);
        ISSUEB(t & 1, (t + 2) * 64);
        asm volatile("s_waitcnt vmcnt(7)" ::: "memory");  // B(t+1) landed
      } else {
        asm volatile("s_waitcnt vmcnt(0)" ::: "memory");  // final drain
      }
      asm volatile("s_waitcnt lgkmcnt(0)" ::: "memory");
      __builtin_amdgcn_sched_barrier(0);
      __builtin_amdgcn_s_barrier();        // staged tile visible to all
      __builtin_amdgcn_sched_barrier(0);
    }
  }

  // epilogue (verified r5/r6): C/D layout col = lane&15, row = quad*4 + reg
#pragma unroll
  for (int mt = 0; mt < 2; mt++) {
#pragma unroll
    for (int nt = 0; nt < 6; nt++) {
#pragma unroll
      for (int i = 0; i < 4; i++) {
        int row = m0 + mh * 32 + mt * 16 + quad * 4 + i;  // global token index
        int col = nq * 96 + nt * 16 + n;                  // 0..383
        short v = f2bf(acc[mt][nt][i]);
        int w = col >> 7;
        int c = col & 127;          // h index
        int bb = row >> 11;
        int t  = row & (T_DIM - 1);
        int tt = t >> 6;
        if (w == 0) {
          int rr = t & 63;
          int knt = rr >> 4, kn = rr & 15;
          int kc = c >> 5, kq = (c >> 3) & 3, kj = c & 7;
          Kp[(((size_t)(bb * 32 + tt) * 16 + knt * 4 + kc) * 512) +
             (kq * 16 + kn) * 8 + kj] = v;
        } else if (w == 1) {
          Qb[(size_t)row * H_DIM + c] = v;
        } else {
          int vkc = (t >> 5) & 1, vq = (t >> 3) & 3, vj = t & 7;
          int ht = c >> 4, vn = c & 15;
          Vp[(((size_t)(bb * 32 + tt) * 16 + ht * 2 + vkc) * 512) +
             (vq * 16 + vn) * 8 + vj] = v;
        }
      }
    }
  }
}

// ---------------------------------------------------------------------------
// Kernel 3: causal flash attention — unchanged from r6 (verified; < 45.6us).
// Barrier-free main loop; fragment-packed K/V 1KB-segment loads; DPP softmax;
// LPT heavy-first qt order; (256,2) keeps VGPR unclamped (r5 spill lesson).
// ---------------------------------------------------------------------------
__global__ __launch_bounds__(256, 2) void attn_kernel(
    const short* __restrict__ Qb, const short* __restrict__ Kp,
    const short* __restrict__ Vp, float* __restrict__ out) {
  const int id = blockIdx.y * 128 + blockIdx.x;
  const int b  = id & 7;             // batch -> XCD spread
  const int qt = 127 - (id >> 3);    // heavy-first (LPT)
  const int q0 = qt * 16;
  const int tid  = threadIdx.x;
  const int lane = tid & 63;
  const int g    = tid >> 6;   // kv phase 0..3
  const int n    = lane & 15;
  const int quad = lane >> 4;

  __shared__ short Ps[4][16][72];   // per-wave P strips (9.2KB)
  __shared__ float Om[16][128];     // merge buffer (8KB)
  __shared__ float Ml[16][2];

  const int ntiles = (qt >> 2) + 1;
  const float scale = 0.08838834764831845f;  // 1/sqrt(128)
  const int row0 = q0 + quad * 4;            // + reg i

  const short* Kbase = Kp + (size_t)b * 32 * 16 * 512;
  const short* Vbase = Vp + (size_t)b * 32 * 16 * 512;

  // Q A-frags (same for all 4 waves)
  bf16x8 aQ[4];
  {
    const short* qrow = Qb + (size_t)(b * T_DIM + q0 + n) * H_DIM;
#pragma unroll
    for (int kc = 0; kc < 4; kc++)
      aQ[kc] = *(const bf16x8*)(qrow + kc * 32 + quad * 8);
  }

  f32x4 accO[8];
#pragma unroll
  for (int i = 0; i < 8; i++) {
    f32x4 z = {0.f, 0.f, 0.f, 0.f};
    accO[i] = z;
  }
  float mrow[4] = {-1e30f, -1e30f, -1e30f, -1e30f};
  float lrow[4] = {0.f, 0.f, 0.f, 0.f};

  for (int t = g; t < ntiles; t += 4) {
    const int j0 = t * 64;
    const short* Kt = Kbase + (size_t)t * 16 * 512 + lane * 8;
    const short* Vt = Vbase + (size_t)t * 16 * 512 + lane * 8;
    f32x4 accS[4];
#pragma unroll
    for (int nt = 0; nt < 4; nt++) {
      f32x4 z = {0.f, 0.f, 0.f, 0.f};
      accS[nt] = z;
    }
    // ---- K: all 16 coalesced 1KB loads in flight, then 16 MFMAs ----
    bf16x8 fr[16];
#pragma unroll
    for (int nt = 0; nt < 4; nt++)
#pragma unroll
      for (int kc = 0; kc < 4; kc++)
        fr[nt * 4 + kc] = *(const bf16x8*)(Kt + (nt * 4 + kc) * 512);
    __builtin_amdgcn_sched_barrier(0);
#pragma unroll
    for (int nt = 0; nt < 4; nt++)
#pragma unroll
      for (int kc = 0; kc < 4; kc++)
        accS[nt] = __builtin_amdgcn_mfma_f32_16x16x32_bf16(
            aQ[kc], fr[nt * 4 + kc], accS[nt], 0, 0, 0);
    __builtin_amdgcn_sched_barrier(0);

    // ---- scale + causal mask + row max (DPP) ----
    float mt4[4] = {-1e30f, -1e30f, -1e30f, -1e30f};
#pragma unroll
    for (int nt = 0; nt < 4; nt++) {
      int col = j0 + nt * 16 + n;
#pragma unroll
      for (int i = 0; i < 4; i++) {
        float s = accS[nt][i] * scale;
        s = (col > row0 + i) ? -1e30f : s;
        accS[nt][i] = s;
        mt4[i] = fmaxf(mt4[i], s);
      }
    }
#pragma unroll
    for (int i = 0; i < 4; i++) mt4[i] = rowmax16(mt4[i]);

    // ---- V batch 0 prefetch under softmax ----
    bf16x8 frv[8];
#pragma unroll
    for (int ht = 0; ht < 4; ht++)
#pragma unroll
      for (int kc = 0; kc < 2; kc++)
        frv[ht * 2 + kc] = *(const bf16x8*)(Vt + (ht * 2 + kc) * 512);
    __builtin_amdgcn_sched_barrier(0);

    // ---- softmax ----
    float alpha[4], rsum[4];
#pragma unroll
    for (int i = 0; i < 4; i++) {
      float mnew = fmaxf(mrow[i], mt4[i]);
      alpha[i] = __expf(mrow[i] - mnew);
      mrow[i] = mnew;
      rsum[i] = 0.f;
    }
#pragma unroll
    for (int nt = 0; nt < 4; nt++)
#pragma unroll
      for (int i = 0; i < 4; i++) {
        float p = __expf(accS[nt][i] - mrow[i]);
        rsum[i] += p;
        Ps[g][quad * 4 + i][nt * 16 + n] = f2bf(p);
      }
#pragma unroll
    for (int i = 0; i < 4; i++) {
      rsum[i] = rowsum16(rsum[i]);
      lrow[i] = lrow[i] * alpha[i] + rsum[i];
    }
#pragma unroll
    for (int ht = 0; ht < 8; ht++)
#pragma unroll
      for (int i = 0; i < 4; i++)
        accO[ht][i] *= alpha[i];

    // P strip written+read by the SAME wave: lgkmcnt wait suffices (rule 18)
    asm volatile("s_waitcnt lgkmcnt(0)" ::: "memory");
    __builtin_amdgcn_sched_barrier(0);

    bf16x8 aP[2];
#pragma unroll
    for (int kc = 0; kc < 2; kc++)
      aP[kc] = *(const bf16x8*)&Ps[g][n][kc * 32 + quad * 8];

    // ---- PV batch 0 (ht 0..3) ----
#pragma unroll
    for (int ht = 0; ht < 4; ht++)
#pragma unroll
      for (int kc = 0; kc < 2; kc++)
        accO[ht] = __builtin_amdgcn_mfma_f32_16x16x32_bf16(
            aP[kc], frv[ht * 2 + kc], accO[ht], 0, 0, 0);
    __builtin_amdgcn_sched_barrier(0);
    // ---- V batch 1 (ht 4..7) ----
#pragma unroll
    for (int ht = 0; ht < 4; ht++)
#pragma unroll
      for (int kc = 0; kc < 2; kc++)
        frv[ht * 2 + kc] = *(const bf16x8*)(Vt + ((ht + 4) * 2 + kc) * 512);
    __builtin_amdgcn_sched_barrier(0);
#pragma unroll
    for (int ht = 0; ht < 4; ht++)
#pragma unroll
      for (int kc = 0; kc < 2; kc++)
        accO[ht + 4] = __builtin_amdgcn_mfma_f32_16x16x32_bf16(
            aP[kc], frv[ht * 2 + kc], accO[ht + 4], 0, 0, 0);
  }

  // ---- merge the 4 kv-phase partials ----
  __syncthreads();
  if (g == 0) {
#pragma unroll
    for (int i = 0; i < 4; i++) {
      int r = quad * 4 + i;
#pragma unroll
      for (int ht = 0; ht < 8; ht++)
        Om[r][ht * 16 + n] = accO[ht][i];
      if (n == 0) { Ml[r][0] = mrow[i]; Ml[r][1] = lrow[i]; }
    }
  }
#pragma unroll
  for (int gg = 1; gg < 4; gg++) {
    __syncthreads();
    if (g == gg) {
#pragma unroll
      for (int i = 0; i < 4; i++) {
        int r = quad * 4 + i;
        float m1 = Ml[r][0], l1 = Ml[r][1];
        float mnew = fmaxf(mrow[i], m1);
        float a0 = __expf(mrow[i] - mnew);   // 0 when this phase had no tiles
        float a1 = __expf(m1 - mnew);
        float lnew = lrow[i] * a0 + l1 * a1;
        if (gg < 3) {
          if (n == 0) { Ml[r][0] = mnew; Ml[r][1] = lnew; }
#pragma unroll
          for (int ht = 0; ht < 8; ht++)
            Om[r][ht * 16 + n] = accO[ht][i] * a0 + Om[r][ht * 16 + n] * a1;
        } else {
          float linv = 1.0f / lnew;
          size_t base = (size_t)(b * T_DIM + q0 + r) * H_DIM;
#pragma unroll
          for (int ht = 0; ht < 8; ht++)
            out[base + ht * 16 + n] =
                (accO[ht][i] * a0 + Om[r][ht * 16 + n] * a1) * linv;
        }
      }
    }
  }
}

// ---------------------------------------------------------------------------
extern "C" void kernel_launch(void* const* d_in, const int* in_sizes, int n_in,
                              void* d_out, int out_size, void* d_ws, size_t ws_size,
                              hipStream_t stream) {
  (void)in_sizes; (void)n_in; (void)out_size; (void)ws_size;
  const float* x  = (const float*)d_in[0];
  const float* Wk = (const float*)d_in[1];
  const float* Wq = (const float*)d_in[2];
  const float* Wv = (const float*)d_in[3];
  float* out = (float*)d_out;

  char* ws = (char*)d_ws;
  short* Wt = (short*)ws;                               // 786,432 B
  short* Kp = (short*)(ws + 786432);                    // 4 MB (fragment-packed)
  short* Qb = (short*)(ws + 786432 + 4194304);          // 4 MB
  short* Vp = (short*)(ws + 786432 + 8388608);          // 4 MB (fragment-packed)

  wprep_kernel<<<dim3(192), dim3(256), 0, stream>>>(Wk, Wq, Wv, Wt);
  projf_kernel<<<dim3(256), dim3(512), 0, stream>>>(x, Wt, Kp, Qb, Vp);
  attn_kernel<<<dim3(128, 8), dim3(256), 0, stream>>>(Qb, Kp, Vp, out);
}

// Round 8
// 157.988 us; speedup vs baseline: 1.8241x; 1.0006x over previous
//
#include <hip/hip_runtime.h>

#define B_DIM 8
#define T_DIM 2048
#define C_DIM 1024
#define H_DIM 128

typedef __attribute__((ext_vector_type(8))) short bf16x8;
typedef __attribute__((ext_vector_type(4))) float f32x4;

__device__ __forceinline__ short f2bf(float f) {
  union { float f; unsigned u; } v; v.f = f;
  unsigned u = v.u;
  unsigned r = (u + 0x7FFFu + ((u >> 16) & 1u)) >> 16;
  return (short)r;
}

__device__ __forceinline__ void gload_lds16(const short* g, short* l) {
  __builtin_amdgcn_global_load_lds(
      (const __attribute__((address_space(1))) void*)g,
      (__attribute__((address_space(3))) void*)l, 16, 0, 0);
}

// DPP rotate-reduce over the 16-lane row (n = lane&15), VALU-speed.
__device__ __forceinline__ float rowmax16(float x) {
  union { float f; int i; } a, t;
  a.f = x;
  t.i = __builtin_amdgcn_update_dpp(a.i, a.i, 0x128, 0xf, 0xf, false);  // ror:8
  a.f = fmaxf(a.f, t.f);
  t.i = __builtin_amdgcn_update_dpp(a.i, a.i, 0x124, 0xf, 0xf, false);  // ror:4
  a.f = fmaxf(a.f, t.f);
  t.i = __builtin_amdgcn_update_dpp(a.i, a.i, 0x122, 0xf, 0xf, false);  // ror:2
  a.f = fmaxf(a.f, t.f);
  t.i = __builtin_amdgcn_update_dpp(a.i, a.i, 0x121, 0xf, 0xf, false);  // ror:1
  a.f = fmaxf(a.f, t.f);
  return a.f;
}
__device__ __forceinline__ float rowsum16(float x) {
  union { float f; int i; } a, t;
  a.f = x;
  t.i = __builtin_amdgcn_update_dpp(a.i, a.i, 0x128, 0xf, 0xf, false);
  a.f += t.f;
  t.i = __builtin_amdgcn_update_dpp(a.i, a.i, 0x124, 0xf, 0xf, false);
  a.f += t.f;
  t.i = __builtin_amdgcn_update_dpp(a.i, a.i, 0x122, 0xf, 0xf, false);
  a.f += t.f;
  t.i = __builtin_amdgcn_update_dpp(a.i, a.i, 0x121, 0xf, 0xf, false);
  a.f += t.f;
  return a.f;
}

// ---------------------------------------------------------------------------
// Kernel 1: weight prep (1.5 MB).  Wt[3][H=128][C=1024] bf16, 16B writes.
// ---------------------------------------------------------------------------
#define NWE ((3 * C_DIM * H_DIM) / 8)       // 49152 items

__global__ __launch_bounds__(256) void wprep_kernel(
    const float* __restrict__ Wk, const float* __restrict__ Wq,
    const float* __restrict__ Wv, short* __restrict__ Wt) {
  int j = blockIdx.x * 256 + threadIdx.x;
  if (j >= NWE) return;
  int w = j >> 14;             // 16384 items per weight
  int r = j & 16383;
  int h = r >> 7;              // C/8 = 128 items per h
  int c0 = (r & 127) * 8;
  const float* W = (w == 0) ? Wk : ((w == 1) ? Wq : Wv);
  __attribute__((aligned(16))) short t[8];
#pragma unroll
  for (int i = 0; i < 8; i++) t[i] = f2bf(W[(size_t)(c0 + i) * H_DIM + h]);
  *(int4*)(Wt + (size_t)w * (C_DIM * H_DIM) + h * C_DIM + c0) = *(const int4*)t;
}

// ---------------------------------------------------------------------------
// Kernel 2: fused projection v4 = v3 with the vmcnt OFF-BY-ONE fixed.
// r7's vmcnt(7) retired B(t+1)x6 PLUS the first A(t+2) load (LOADA = TWO
// dwordx4s, queue depth 14 not 13) -> stalled ~900cy on a just-issued HBM
// load every iter = r6 behavior, measured identical 47us.  vmcnt(8) leaves
// {A(t+2)x2, B(t+2)x6} = 8 in flight and retires exactly B(t+1)x6, which
// are a full compute-phase old (L2-resident Wt, already landed).  Verified
// for both possible compiler emission orders of the staging clump, the
// prologue (14 -> retire B(0)x6), and the t=14 full drain.
// ---------------------------------------------------------------------------
__global__ __launch_bounds__(512, 2) void projf_kernel(
    const float* __restrict__ x, const short* __restrict__ Wt,
    short* __restrict__ Kp, short* __restrict__ Qb, short* __restrict__ Vp) {
  const int m0 = blockIdx.x * 64;
  __shared__ short As[2][64][72];     // 18.4 KB (pitch 144B, 2-way free)
  __shared__ short Bs[2][384 * 64];   // 96 KB, linear; storage XOR-swizzled
  const int tid  = threadIdx.x;
  const int lane = tid & 63;
  const int wv   = tid >> 6;
  const int n    = lane & 15;
  const int quad = lane >> 4;
  const int mh = wv >> 2;        // 0..1: rows mh*32 .. +32
  const int nq = wv & 3;         // 0..3: cols nq*96 .. +96

  const int ar = tid >> 3, ac = (tid & 7) * 8;
  const float* xrow = x + (size_t)(m0 + ar) * C_DIM + ac;
  const int brl = lane >> 3;                    // row within 8x128B chunk
  const int bce = 8 * ((lane & 7) ^ brl);       // pre-swizzled elem offset

  f32x4 acc[2][6];
#pragma unroll
  for (int i = 0; i < 2; i++)
#pragma unroll
    for (int j = 0; j < 6; j++) {
      f32x4 z = {0.f, 0.f, 0.f, 0.f};
      acc[i][j] = z;
    }

  float4 a0x, a0y, a1x, a1y;   // two A reg sets (static indexing, rule 20)

  auto LOADA = [&](int k0, float4& u, float4& v) {
    u = *(const float4*)(xrow + k0);
    v = *(const float4*)(xrow + k0 + 4);
  };
  auto STOREA = [&](int buf, const float4& u, const float4& v) {
    __attribute__((aligned(16))) short t8[8];
    t8[0] = f2bf(u.x); t8[1] = f2bf(u.y); t8[2] = f2bf(u.z); t8[3] = f2bf(u.w);
    t8[4] = f2bf(v.x); t8[5] = f2bf(v.y); t8[6] = f2bf(v.z); t8[7] = f2bf(v.w);
    *(int4*)&As[buf][ar][ac] = *(const int4*)t8;
  };
  auto ISSUEB = [&](int buf, int k0) {
#pragma unroll
    for (int h = 0; h < 6; h++) {
      int c = wv * 6 + h;
      gload_lds16(Wt + (size_t)(c * 8 + brl) * C_DIM + k0 + bce,
                  &Bs[buf][c * 512]);
    }
  };
  auto COMPUTE = [&](int buf) {
#pragma unroll
    for (int kk = 0; kk < 2; kk++) {
      bf16x8 aF[2], bF[6];
#pragma unroll
      for (int mt = 0; mt < 2; mt++)
        aF[mt] = *(const bf16x8*)&As[buf][mh * 32 + mt * 16 + n][kk * 32 + quad * 8];
#pragma unroll
      for (int nt = 0; nt < 6; nt++) {
        int row = nq * 96 + nt * 16 + n;
        int off = (kk * 64 + quad * 16) ^ ((row & 7) << 4);   // bytes
        bF[nt] = *(const bf16x8*)((const char*)&Bs[buf][row * 64] + off);
      }
#pragma unroll
      for (int mt = 0; mt < 2; mt++)
#pragma unroll
        for (int nt = 0; nt < 6; nt++)
          acc[mt][nt] = __builtin_amdgcn_mfma_f32_16x16x32_bf16(
              aF[mt], bF[nt], acc[mt][nt], 0, 0, 0);
    }
  };

  // prologue: establish invariant {A(t+1)x2, B(t+1)x6} = 8 outstanding
  LOADA(0, a0x, a0y);
  ISSUEB(0, 0);
  STOREA(0, a0x, a0y);             // compiler auto-waits for A(0)
  LOADA(64, a1x, a1y);
  ISSUEB(1, 64);
  asm volatile("s_waitcnt vmcnt(8)" ::: "memory");   // retire B(0)x6 only
  asm volatile("s_waitcnt lgkmcnt(0)" ::: "memory"); // As(0) written
  __builtin_amdgcn_sched_barrier(0);
  __builtin_amdgcn_s_barrier();
  __builtin_amdgcn_sched_barrier(0);

#pragma unroll
  for (int t = 0; t < 16; ++t) {
    COMPUTE(t & 1);
    if (t < 15) {
      __builtin_amdgcn_s_barrier();        // all waves done reading buf[t&1]
      __builtin_amdgcn_sched_barrier(0);
      if ((t & 1) == 0) STOREA(1, a1x, a1y);   // As[(t+1)&1], set loaded @t-1
      else              STOREA(0, a0x, a0y);
      if (t + 2 < 16) {
        if ((t & 1) == 0) LOADA((t + 2) * 64, a0x, a0y);
        else              LOADA((t + 2) * 64, a1x, a1y);
        ISSUEB(t & 1, (t + 2) * 64);
        // queue: [B(t+1)x6, A(t+2)x2, B(t+2)x6] = 14; retire exactly B(t+1)
        asm volatile("s_waitcnt vmcnt(8)" ::: "memory");
      } else {
        asm volatile("s_waitcnt vmcnt(0)" ::: "memory");  // final drain
      }
      asm volatile("s_waitcnt lgkmcnt(0)" ::: "memory");
      __builtin_amdgcn_sched_barrier(0);
      __builtin_amdgcn_s_barrier();        // staged tile visible to all
      __builtin_amdgcn_sched_barrier(0);
    }
  }

  // epilogue (verified r5/r6): C/D layout col = lane&15, row = quad*4 + reg
#pragma unroll
  for (int mt = 0; mt < 2; mt++) {
#pragma unroll
    for (int nt = 0; nt < 6; nt++) {
#pragma unroll
      for (int i = 0; i < 4; i++) {
        int row = m0 + mh * 32 + mt * 16 + quad * 4 + i;  // global token index
        int col = nq * 96 + nt * 16 + n;                  // 0..383
        short v = f2bf(acc[mt][nt][i]);
        int w = col >> 7;
        int c = col & 127;          // h index
        int bb = row >> 11;
        int t  = row & (T_DIM - 1);
        int tt = t >> 6;
        if (w == 0) {
          int rr = t & 63;
          int knt = rr >> 4, kn = rr & 15;
          int kc = c >> 5, kq = (c >> 3) & 3, kj = c & 7;
          Kp[(((size_t)(bb * 32 + tt) * 16 + knt * 4 + kc) * 512) +
             (kq * 16 + kn) * 8 + kj] = v;
        } else if (w == 1) {
          Qb[(size_t)row * H_DIM + c] = v;
        } else {
          int vkc = (t >> 5) & 1, vq = (t >> 3) & 3, vj = t & 7;
          int ht = c >> 4, vn = c & 15;
          Vp[(((size_t)(bb * 32 + tt) * 16 + ht * 2 + vkc) * 512) +
             (vq * 16 + vn) * 8 + vj] = v;
        }
      }
    }
  }
}

// ---------------------------------------------------------------------------
// Kernel 3: causal flash attention — unchanged (r6-verified; < 45.6us).
// Barrier-free main loop; fragment-packed K/V 1KB-segment loads; DPP softmax;
// LPT heavy-first qt order; (256,2) keeps VGPR unclamped (r5 spill lesson).
// ---------------------------------------------------------------------------
__global__ __launch_bounds__(256, 2) void attn_kernel(
    const short* __restrict__ Qb, const short* __restrict__ Kp,
    const short* __restrict__ Vp, float* __restrict__ out) {
  const int id = blockIdx.y * 128 + blockIdx.x;
  const int b  = id & 7;             // batch -> XCD spread
  const int qt = 127 - (id >> 3);    // heavy-first (LPT)
  const int q0 = qt * 16;
  const int tid  = threadIdx.x;
  const int lane = tid & 63;
  const int g    = tid >> 6;   // kv phase 0..3
  const int n    = lane & 15;
  const int quad = lane >> 4;

  __shared__ short Ps[4][16][72];   // per-wave P strips (9.2KB)
  __shared__ float Om[16][128];     // merge buffer (8KB)
  __shared__ float Ml[16][2];

  const int ntiles = (qt >> 2) + 1;
  const float scale = 0.08838834764831845f;  // 1/sqrt(128)
  const int row0 = q0 + quad * 4;            // + reg i

  const short* Kbase = Kp + (size_t)b * 32 * 16 * 512;
  const short* Vbase = Vp + (size_t)b * 32 * 16 * 512;

  // Q A-frags (same for all 4 waves)
  bf16x8 aQ[4];
  {
    const short* qrow = Qb + (size_t)(b * T_DIM + q0 + n) * H_DIM;
#pragma unroll
    for (int kc = 0; kc < 4; kc++)
      aQ[kc] = *(const bf16x8*)(qrow + kc * 32 + quad * 8);
  }

  f32x4 accO[8];
#pragma unroll
  for (int i = 0; i < 8; i++) {
    f32x4 z = {0.f, 0.f, 0.f, 0.f};
    accO[i] = z;
  }
  float mrow[4] = {-1e30f, -1e30f, -1e30f, -1e30f};
  float lrow[4] = {0.f, 0.f, 0.f, 0.f};

  for (int t = g; t < ntiles; t += 4) {
    const int j0 = t * 64;
    const short* Kt = Kbase + (size_t)t * 16 * 512 + lane * 8;
    const short* Vt = Vbase + (size_t)t * 16 * 512 + lane * 8;
    f32x4 accS[4];
#pragma unroll
    for (int nt = 0; nt < 4; nt++) {
      f32x4 z = {0.f, 0.f, 0.f, 0.f};
      accS[nt] = z;
    }
    // ---- K: all 16 coalesced 1KB loads in flight, then 16 MFMAs ----
    bf16x8 fr[16];
#pragma unroll
    for (int nt = 0; nt < 4; nt++)
#pragma unroll
      for (int kc = 0; kc < 4; kc++)
        fr[nt * 4 + kc] = *(const bf16x8*)(Kt + (nt * 4 + kc) * 512);
    __builtin_amdgcn_sched_barrier(0);
#pragma unroll
    for (int nt = 0; nt < 4; nt++)
#pragma unroll
      for (int kc = 0; kc < 4; kc++)
        accS[nt] = __builtin_amdgcn_mfma_f32_16x16x32_bf16(
            aQ[kc], fr[nt * 4 + kc], accS[nt], 0, 0, 0);
    __builtin_amdgcn_sched_barrier(0);

    // ---- scale + causal mask + row max (DPP) ----
    float mt4[4] = {-1e30f, -1e30f, -1e30f, -1e30f};
#pragma unroll
    for (int nt = 0; nt < 4; nt++) {
      int col = j0 + nt * 16 + n;
#pragma unroll
      for (int i = 0; i < 4; i++) {
        float s = accS[nt][i] * scale;
        s = (col > row0 + i) ? -1e30f : s;
        accS[nt][i] = s;
        mt4[i] = fmaxf(mt4[i], s);
      }
    }
#pragma unroll
    for (int i = 0; i < 4; i++) mt4[i] = rowmax16(mt4[i]);

    // ---- V batch 0 prefetch under softmax ----
    bf16x8 frv[8];
#pragma unroll
    for (int ht = 0; ht < 4; ht++)
#pragma unroll
      for (int kc = 0; kc < 2; kc++)
        frv[ht * 2 + kc] = *(const bf16x8*)(Vt + (ht * 2 + kc) * 512);
    __builtin_amdgcn_sched_barrier(0);

    // ---- softmax ----
    float alpha[4], rsum[4];
#pragma unroll
    for (int i = 0; i < 4; i++) {
      float mnew = fmaxf(mrow[i], mt4[i]);
      alpha[i] = __expf(mrow[i] - mnew);
      mrow[i] = mnew;
      rsum[i] = 0.f;
    }
#pragma unroll
    for (int nt = 0; nt < 4; nt++)
#pragma unroll
      for (int i = 0; i < 4; i++) {
        float p = __expf(accS[nt][i] - mrow[i]);
        rsum[i] += p;
        Ps[g][quad * 4 + i][nt * 16 + n] = f2bf(p);
      }
#pragma unroll
    for (int i = 0; i < 4; i++) {
      rsum[i] = rowsum16(rsum[i]);
      lrow[i] = lrow[i] * alpha[i] + rsum[i];
    }
#pragma unroll
    for (int ht = 0; ht < 8; ht++)
#pragma unroll
      for (int i = 0; i < 4; i++)
        accO[ht][i] *= alpha[i];

    // P strip written+read by the SAME wave: lgkmcnt wait suffices (rule 18)
    asm volatile("s_waitcnt lgkmcnt(0)" ::: "memory");
    __builtin_amdgcn_sched_barrier(0);

    bf16x8 aP[2];
#pragma unroll
    for (int kc = 0; kc < 2; kc++)
      aP[kc] = *(const bf16x8*)&Ps[g][n][kc * 32 + quad * 8];

    // ---- PV batch 0 (ht 0..3) ----
#pragma unroll
    for (int ht = 0; ht < 4; ht++)
#pragma unroll
      for (int kc = 0; kc < 2; kc++)
        accO[ht] = __builtin_amdgcn_mfma_f32_16x16x32_bf16(
            aP[kc], frv[ht * 2 + kc], accO[ht], 0, 0, 0);
    __builtin_amdgcn_sched_barrier(0);
    // ---- V batch 1 (ht 4..7) ----
#pragma unroll
    for (int ht = 0; ht < 4; ht++)
#pragma unroll
      for (int kc = 0; kc < 2; kc++)
        frv[ht * 2 + kc] = *(const bf16x8*)(Vt + ((ht + 4) * 2 + kc) * 512);
    __builtin_amdgcn_sched_barrier(0);
#pragma unroll
    for (int ht = 0; ht < 4; ht++)
#pragma unroll
      for (int kc = 0; kc < 2; kc++)
        accO[ht + 4] = __builtin_amdgcn_mfma_f32_16x16x32_bf16(
            aP[kc], frv[ht * 2 + kc], accO[ht + 4], 0, 0, 0);
  }

  // ---- merge the 4 kv-phase partials ----
  __syncthreads();
  if (g == 0) {
#pragma unroll
    for (int i = 0; i < 4; i++) {
      int r = quad * 4 + i;
#pragma unroll
      for (int ht = 0; ht < 8; ht++)
        Om[r][ht * 16 + n] = accO[ht][i];
      if (n == 0) { Ml[r][0] = mrow[i]; Ml[r][1] = lrow[i]; }
    }
  }
#pragma unroll
  for (int gg = 1; gg < 4; gg++) {
    __syncthreads();
    if (g == gg) {
#pragma unroll
      for (int i = 0; i < 4; i++) {
        int r = quad * 4 + i;
        float m1 = Ml[r][0], l1 = Ml[r][1];
        float mnew = fmaxf(mrow[i], m1);
        float a0 = __expf(mrow[i] - mnew);   // 0 when this phase had no tiles
        float a1 = __expf(m1 - mnew);
        float lnew = lrow[i] * a0 + l1 * a1;
        if (gg < 3) {
          if (n == 0) { Ml[r][0] = mnew; Ml[r][1] = lnew; }
#pragma unroll
          for (int ht = 0; ht < 8; ht++)
            Om[r][ht * 16 + n] = accO[ht][i] * a0 + Om[r][ht * 16 + n] * a1;
        } else {
          float linv = 1.0f / lnew;
          size_t base = (size_t)(b * T_DIM + q0 + r) * H_DIM;
#pragma unroll
          for (int ht = 0; ht < 8; ht++)
            out[base + ht * 16 + n] =
                (accO[ht][i] * a0 + Om[r][ht * 16 + n] * a1) * linv;
        }
      }
    }
  }
}

// ---------------------------------------------------------------------------
extern "C" void kernel_launch(void* const* d_in, const int* in_sizes, int n_in,
                              void* d_out, int out_size, void* d_ws, size_t ws_size,
                              hipStream_t stream) {
  (void)in_sizes; (void)n_in; (void)out_size; (void)ws_size;
  const float* x  = (const float*)d_in[0];
  const float* Wk = (const float*)d_in[1];
  const float* Wq = (const float*)d_in[2];
  const float* Wv = (const float*)d_in[3];
  float* out = (float*)d_out;

  char* ws = (char*)d_ws;
  short* Wt = (short*)ws;                               // 786,432 B
  short* Kp = (short*)(ws + 786432);                    // 4 MB (fragment-packed)
  short* Qb = (short*)(ws + 786432 + 4194304);          // 4 MB
  short* Vp = (short*)(ws + 786432 + 8388608);          // 4 MB (fragment-packed)

  wprep_kernel<<<dim3(192), dim3(256), 0, stream>>>(Wk, Wq, Wv, Wt);
  projf_kernel<<<dim3(256), dim3(512), 0, stream>>>(x, Wt, Kp, Qb, Vp);
  attn_kernel<<<dim3(128, 8), dim3(256), 0, stream>>>(Qb, Kp, Vp, out);
}

// Round 9
// 151.096 us; speedup vs baseline: 1.9073x; 1.0456x over previous
//
#include <hip/hip_runtime.h>

#define B_DIM 8
#define T_DIM 2048
#define C_DIM 1024
#define H_DIM 128

typedef __attribute__((ext_vector_type(8))) short bf16x8;
typedef __attribute__((ext_vector_type(4))) float f32x4;

__device__ __forceinline__ short f2bf(float f) {
  union { float f; unsigned u; } v; v.f = f;
  unsigned u = v.u;
  unsigned r = (u + 0x7FFFu + ((u >> 16) & 1u)) >> 16;
  return (short)r;
}

// DPP rotate-reduce over the 16-lane row (n = lane&15), VALU-speed.
__device__ __forceinline__ float rowmax16(float x) {
  union { float f; int i; } a, t;
  a.f = x;
  t.i = __builtin_amdgcn_update_dpp(a.i, a.i, 0x128, 0xf, 0xf, false);  // ror:8
  a.f = fmaxf(a.f, t.f);
  t.i = __builtin_amdgcn_update_dpp(a.i, a.i, 0x124, 0xf, 0xf, false);  // ror:4
  a.f = fmaxf(a.f, t.f);
  t.i = __builtin_amdgcn_update_dpp(a.i, a.i, 0x122, 0xf, 0xf, false);  // ror:2
  a.f = fmaxf(a.f, t.f);
  t.i = __builtin_amdgcn_update_dpp(a.i, a.i, 0x121, 0xf, 0xf, false);  // ror:1
  a.f = fmaxf(a.f, t.f);
  return a.f;
}
__device__ __forceinline__ float rowsum16(float x) {
  union { float f; int i; } a, t;
  a.f = x;
  t.i = __builtin_amdgcn_update_dpp(a.i, a.i, 0x128, 0xf, 0xf, false);
  a.f += t.f;
  t.i = __builtin_amdgcn_update_dpp(a.i, a.i, 0x124, 0xf, 0xf, false);
  a.f += t.f;
  t.i = __builtin_amdgcn_update_dpp(a.i, a.i, 0x122, 0xf, 0xf, false);
  a.f += t.f;
  t.i = __builtin_amdgcn_update_dpp(a.i, a.i, 0x121, 0xf, 0xf, false);
  a.f += t.f;
  return a.f;
}

// ---------------------------------------------------------------------------
// Kernel 1: weight prep (1.5 MB) -> MFMA-FRAGMENT-PACKED Wtp.
// Element (colg = w*128+h, c): nt=colg>>4, nn=colg&15, kc=c>>5, quad=(c>>3)&3,
// j=c&7 -> Wtp[((nt*32+kc)*64 + quad*16 + nn)*8 + j].  A projf B-frag load is
// then base + lane*16B: ONE contiguous 1KB L2 segment (no LDS staging at all).
// ---------------------------------------------------------------------------
#define NWE ((3 * C_DIM * H_DIM) / 8)       // 49152 items

__global__ __launch_bounds__(256) void wprep_kernel(
    const float* __restrict__ Wk, const float* __restrict__ Wq,
    const float* __restrict__ Wv, short* __restrict__ Wtp) {
  int j = blockIdx.x * 256 + threadIdx.x;
  if (j >= NWE) return;
  int w = j >> 14;             // 16384 items per weight
  int r = j & 16383;
  int h = r >> 7;              // C/8 = 128 items per h
  int c0 = (r & 127) * 8;
  const float* W = (w == 0) ? Wk : ((w == 1) ? Wq : Wv);
  __attribute__((aligned(16))) short t[8];
#pragma unroll
  for (int i = 0; i < 8; i++) t[i] = f2bf(W[(size_t)(c0 + i) * H_DIM + h]);
  int colg = w * 128 + h;
  int nt = colg >> 4, nn = colg & 15;
  int kc = c0 >> 5, quad = (c0 >> 3) & 3;
  *(int4*)(Wtp + ((size_t)(nt * 32 + kc) * 64 + quad * 16 + nn) * 8) =
      *(const int4*)t;
}

// ---------------------------------------------------------------------------
// Kernel 2: fused projection v5 — TLP design.  r6-r8 proved counted-vmcnt
// can't fix a 1-block/CU lockstep structure (46/48/58us, nothing >10% busy).
// Changes: (a) B is NOT LDS-staged -- it is 768KB L2-resident, read as
// fragment-packed 1KB segments directly (attn lesson, common-mistake #7);
// (b) tile 32 rows x 384 cols, grid 512 = 2 blocks/CU, 8 waves x 48 cols;
// (c) only A (x fp32->bf16 transpose) goes through LDS: 9KB double-buffer,
// distance-2 reg prefetch, plain 2-barrier loop.  Latency hidden by 16
// waves/CU of TLP, not hand-scheduling.
// ---------------------------------------------------------------------------
__global__ __launch_bounds__(512, 2) void projf_kernel(
    const float* __restrict__ x, const short* __restrict__ Wtp,
    short* __restrict__ Kp, short* __restrict__ Qb, short* __restrict__ Vp) {
  const int m0 = blockIdx.x * 32;
  __shared__ short As[2][32][72];     // 9.2 KB (pitch 144B, 2-way free)
  const int tid  = threadIdx.x;
  const int lane = tid & 63;
  const int wv   = tid >> 6;
  const int n    = lane & 15;
  const int quad = lane >> 4;

  // A staging: thread -> row tid>>4 (0..31), 4 floats at (tid&15)*4
  const int ar = tid >> 4, ac4 = (tid & 15) * 4;
  const float* xrow = x + (size_t)(m0 + ar) * C_DIM + ac4;
  // per-wave B fragment base (lane*16B within each 1KB fragment)
  const short* Bw = Wtp + (size_t)(wv * 3) * 32 * 512 + lane * 8;

  f32x4 acc[2][3];
#pragma unroll
  for (int i = 0; i < 2; i++)
#pragma unroll
    for (int j = 0; j < 3; j++) {
      f32x4 z = {0.f, 0.f, 0.f, 0.f};
      acc[i][j] = z;
    }

  float4 s0, s1;   // two A reg sets: tile t lives in s[t&1] (rule 20: static)
  auto LOADA = [&](int it, float4& s) { s = *(const float4*)(xrow + it * 64); };
  auto STOREA = [&](int buf, const float4& s) {
    __attribute__((aligned(8))) short t4[4];
    t4[0] = f2bf(s.x); t4[1] = f2bf(s.y); t4[2] = f2bf(s.z); t4[3] = f2bf(s.w);
    *(int2*)&As[buf][ar][ac4] = *(const int2*)t4;
  };

  LOADA(0, s0);
  STOREA(0, s0);          // compiler waits for s0
  LOADA(1, s1);           // tile1 in flight across first compute
  __syncthreads();

#pragma unroll 2
  for (int it = 0; it < 16; ++it) {
    // ---- compute on As[it&1]: 6 B-frag loads (L2) + 4 A ds_reads + 12 MFMA
    bf16x8 bF[6], aF[4];
#pragma unroll
    for (int ntl = 0; ntl < 3; ntl++)
#pragma unroll
      for (int kk = 0; kk < 2; kk++)
        bF[ntl * 2 + kk] =
            *(const bf16x8*)(Bw + (size_t)(ntl * 32 + it * 2 + kk) * 512);
#pragma unroll
    for (int mt = 0; mt < 2; mt++)
#pragma unroll
      for (int kk = 0; kk < 2; kk++)
        aF[mt * 2 + kk] =
            *(const bf16x8*)&As[it & 1][mt * 16 + n][kk * 32 + quad * 8];
    __builtin_amdgcn_sched_barrier(0);
#pragma unroll
    for (int mt = 0; mt < 2; mt++)
#pragma unroll
      for (int ntl = 0; ntl < 3; ntl++)
#pragma unroll
        for (int kk = 0; kk < 2; kk++)
          acc[mt][ntl] = __builtin_amdgcn_mfma_f32_16x16x32_bf16(
              aF[mt * 2 + kk], bF[ntl * 2 + kk], acc[mt][ntl], 0, 0, 0);

    if (it < 15) {
      __syncthreads();                    // all waves done reading As[it&1]
      if (((it + 1) & 1) == 0) STOREA(0, s0); else STOREA(1, s1);
      if (it + 2 < 16) {                  // refill the set just consumed
        if (((it + 2) & 1) == 0) LOADA(it + 2, s0); else LOADA(it + 2, s1);
      }
      __syncthreads();                    // staged tile visible
    }
  }

  // epilogue (verified r5-r8 math): C/D layout col = lane&15, row = quad*4+reg
#pragma unroll
  for (int mt = 0; mt < 2; mt++) {
#pragma unroll
    for (int ntl = 0; ntl < 3; ntl++) {
#pragma unroll
      for (int i = 0; i < 4; i++) {
        int row = m0 + mt * 16 + quad * 4 + i;   // global token index
        int col = wv * 48 + ntl * 16 + n;        // 0..383
        short v = f2bf(acc[mt][ntl][i]);
        int w = col >> 7;
        int c = col & 127;          // h index
        int bb = row >> 11;
        int t  = row & (T_DIM - 1);
        int tt = t >> 6;
        if (w == 0) {
          int rr = t & 63;
          int knt = rr >> 4, kn = rr & 15;
          int kc = c >> 5, kq = (c >> 3) & 3, kj = c & 7;
          Kp[(((size_t)(bb * 32 + tt) * 16 + knt * 4 + kc) * 512) +
             (kq * 16 + kn) * 8 + kj] = v;
        } else if (w == 1) {
          Qb[(size_t)row * H_DIM + c] = v;
        } else {
          int vkc = (t >> 5) & 1, vq = (t >> 3) & 3, vj = t & 7;
          int ht = c >> 4, vn = c & 15;
          Vp[(((size_t)(bb * 32 + tt) * 16 + ht * 2 + vkc) * 512) +
             (vq * 16 + vn) * 8 + vj] = v;
        }
      }
    }
  }
}

// ---------------------------------------------------------------------------
// Kernel 3: causal flash attention — unchanged (r6-verified; < 58us, last
// direct measure 46.9us).  Barrier-free main loop; fragment-packed K/V 1KB
// loads; DPP softmax; LPT heavy-first; (256,2) keeps VGPR unclamped.
// ---------------------------------------------------------------------------
__global__ __launch_bounds__(256, 2) void attn_kernel(
    const short* __restrict__ Qb, const short* __restrict__ Kp,
    const short* __restrict__ Vp, float* __restrict__ out) {
  const int id = blockIdx.y * 128 + blockIdx.x;
  const int b  = id & 7;             // batch -> XCD spread
  const int qt = 127 - (id >> 3);    // heavy-first (LPT)
  const int q0 = qt * 16;
  const int tid  = threadIdx.x;
  const int lane = tid & 63;
  const int g    = tid >> 6;   // kv phase 0..3
  const int n    = lane & 15;
  const int quad = lane >> 4;

  __shared__ short Ps[4][16][72];   // per-wave P strips (9.2KB)
  __shared__ float Om[16][128];     // merge buffer (8KB)
  __shared__ float Ml[16][2];

  const int ntiles = (qt >> 2) + 1;
  const float scale = 0.08838834764831845f;  // 1/sqrt(128)
  const int row0 = q0 + quad * 4;            // + reg i

  const short* Kbase = Kp + (size_t)b * 32 * 16 * 512;
  const short* Vbase = Vp + (size_t)b * 32 * 16 * 512;

  // Q A-frags (same for all 4 waves)
  bf16x8 aQ[4];
  {
    const short* qrow = Qb + (size_t)(b * T_DIM + q0 + n) * H_DIM;
#pragma unroll
    for (int kc = 0; kc < 4; kc++)
      aQ[kc] = *(const bf16x8*)(qrow + kc * 32 + quad * 8);
  }

  f32x4 accO[8];
#pragma unroll
  for (int i = 0; i < 8; i++) {
    f32x4 z = {0.f, 0.f, 0.f, 0.f};
    accO[i] = z;
  }
  float mrow[4] = {-1e30f, -1e30f, -1e30f, -1e30f};
  float lrow[4] = {0.f, 0.f, 0.f, 0.f};

  for (int t = g; t < ntiles; t += 4) {
    const int j0 = t * 64;
    const short* Kt = Kbase + (size_t)t * 16 * 512 + lane * 8;
    const short* Vt = Vbase + (size_t)t * 16 * 512 + lane * 8;
    f32x4 accS[4];
#pragma unroll
    for (int nt = 0; nt < 4; nt++) {
      f32x4 z = {0.f, 0.f, 0.f, 0.f};
      accS[nt] = z;
    }
    // ---- K: all 16 coalesced 1KB loads in flight, then 16 MFMAs ----
    bf16x8 fr[16];
#pragma unroll
    for (int nt = 0; nt < 4; nt++)
#pragma unroll
      for (int kc = 0; kc < 4; kc++)
        fr[nt * 4 + kc] = *(const bf16x8*)(Kt + (nt * 4 + kc) * 512);
    __builtin_amdgcn_sched_barrier(0);
#pragma unroll
    for (int nt = 0; nt < 4; nt++)
#pragma unroll
      for (int kc = 0; kc < 4; kc++)
        accS[nt] = __builtin_amdgcn_mfma_f32_16x16x32_bf16(
            aQ[kc], fr[nt * 4 + kc], accS[nt], 0, 0, 0);
    __builtin_amdgcn_sched_barrier(0);

    // ---- scale + causal mask + row max (DPP) ----
    float mt4[4] = {-1e30f, -1e30f, -1e30f, -1e30f};
#pragma unroll
    for (int nt = 0; nt < 4; nt++) {
      int col = j0 + nt * 16 + n;
#pragma unroll
      for (int i = 0; i < 4; i++) {
        float s = accS[nt][i] * scale;
        s = (col > row0 + i) ? -1e30f : s;
        accS[nt][i] = s;
        mt4[i] = fmaxf(mt4[i], s);
      }
    }
#pragma unroll
    for (int i = 0; i < 4; i++) mt4[i] = rowmax16(mt4[i]);

    // ---- V batch 0 prefetch under softmax ----
    bf16x8 frv[8];
#pragma unroll
    for (int ht = 0; ht < 4; ht++)
#pragma unroll
      for (int kc = 0; kc < 2; kc++)
        frv[ht * 2 + kc] = *(const bf16x8*)(Vt + (ht * 2 + kc) * 512);
    __builtin_amdgcn_sched_barrier(0);

    // ---- softmax ----
    float alpha[4], rsum[4];
#pragma unroll
    for (int i = 0; i < 4; i++) {
      float mnew = fmaxf(mrow[i], mt4[i]);
      alpha[i] = __expf(mrow[i] - mnew);
      mrow[i] = mnew;
      rsum[i] = 0.f;
    }
#pragma unroll
    for (int nt = 0; nt < 4; nt++)
#pragma unroll
      for (int i = 0; i < 4; i++) {
        float p = __expf(accS[nt][i] - mrow[i]);
        rsum[i] += p;
        Ps[g][quad * 4 + i][nt * 16 + n] = f2bf(p);
      }
#pragma unroll
    for (int i = 0; i < 4; i++) {
      rsum[i] = rowsum16(rsum[i]);
      lrow[i] = lrow[i] * alpha[i] + rsum[i];
    }
#pragma unroll
    for (int ht = 0; ht < 8; ht++)
#pragma unroll
      for (int i = 0; i < 4; i++)
        accO[ht][i] *= alpha[i];

    // P strip written+read by the SAME wave: lgkmcnt wait suffices (rule 18)
    asm volatile("s_waitcnt lgkmcnt(0)" ::: "memory");
    __builtin_amdgcn_sched_barrier(0);

    bf16x8 aP[2];
#pragma unroll
    for (int kc = 0; kc < 2; kc++)
      aP[kc] = *(const bf16x8*)&Ps[g][n][kc * 32 + quad * 8];

    // ---- PV batch 0 (ht 0..3) ----
#pragma unroll
    for (int ht = 0; ht < 4; ht++)
#pragma unroll
      for (int kc = 0; kc < 2; kc++)
        accO[ht] = __builtin_amdgcn_mfma_f32_16x16x32_bf16(
            aP[kc], frv[ht * 2 + kc], accO[ht], 0, 0, 0);
    __builtin_amdgcn_sched_barrier(0);
    // ---- V batch 1 (ht 4..7) ----
#pragma unroll
    for (int ht = 0; ht < 4; ht++)
#pragma unroll
      for (int kc = 0; kc < 2; kc++)
        frv[ht * 2 + kc] = *(const bf16x8*)(Vt + ((ht + 4) * 2 + kc) * 512);
    __builtin_amdgcn_sched_barrier(0);
#pragma unroll
    for (int ht = 0; ht < 4; ht++)
#pragma unroll
      for (int kc = 0; kc < 2; kc++)
        accO[ht + 4] = __builtin_amdgcn_mfma_f32_16x16x32_bf16(
            aP[kc], frv[ht * 2 + kc], accO[ht + 4], 0, 0, 0);
  }

  // ---- merge the 4 kv-phase partials ----
  __syncthreads();
  if (g == 0) {
#pragma unroll
    for (int i = 0; i < 4; i++) {
      int r = quad * 4 + i;
#pragma unroll
      for (int ht = 0; ht < 8; ht++)
        Om[r][ht * 16 + n] = accO[ht][i];
      if (n == 0) { Ml[r][0] = mrow[i]; Ml[r][1] = lrow[i]; }
    }
  }
#pragma unroll
  for (int gg = 1; gg < 4; gg++) {
    __syncthreads();
    if (g == gg) {
#pragma unroll
      for (int i = 0; i < 4; i++) {
        int r = quad * 4 + i;
        float m1 = Ml[r][0], l1 = Ml[r][1];
        float mnew = fmaxf(mrow[i], m1);
        float a0 = __expf(mrow[i] - mnew);   // 0 when this phase had no tiles
        float a1 = __expf(m1 - mnew);
        float lnew = lrow[i] * a0 + l1 * a1;
        if (gg < 3) {
          if (n == 0) { Ml[r][0] = mnew; Ml[r][1] = lnew; }
#pragma unroll
          for (int ht = 0; ht < 8; ht++)
            Om[r][ht * 16 + n] = accO[ht][i] * a0 + Om[r][ht * 16 + n] * a1;
        } else {
          float linv = 1.0f / lnew;
          size_t base = (size_t)(b * T_DIM + q0 + r) * H_DIM;
#pragma unroll
          for (int ht = 0; ht < 8; ht++)
            out[base + ht * 16 + n] =
                (accO[ht][i] * a0 + Om[r][ht * 16 + n] * a1) * linv;
        }
      }
    }
  }
}

// ---------------------------------------------------------------------------
extern "C" void kernel_launch(void* const* d_in, const int* in_sizes, int n_in,
                              void* d_out, int out_size, void* d_ws, size_t ws_size,
                              hipStream_t stream) {
  (void)in_sizes; (void)n_in; (void)out_size; (void)ws_size;
  const float* x  = (const float*)d_in[0];
  const float* Wk = (const float*)d_in[1];
  const float* Wq = (const float*)d_in[2];
  const float* Wv = (const float*)d_in[3];
  float* out = (float*)d_out;

  char* ws = (char*)d_ws;
  short* Wtp = (short*)ws;                              // 786,432 B (frag-packed)
  short* Kp = (short*)(ws + 786432);                    // 4 MB (fragment-packed)
  short* Qb = (short*)(ws + 786432 + 4194304);          // 4 MB
  short* Vp = (short*)(ws + 786432 + 8388608);          // 4 MB (fragment-packed)

  wprep_kernel<<<dim3(192), dim3(256), 0, stream>>>(Wk, Wq, Wv, Wtp);
  projf_kernel<<<dim3(512), dim3(512), 0, stream>>>(x, Wtp, Kp, Qb, Vp);
  attn_kernel<<<dim3(128, 8), dim3(256), 0, stream>>>(Qb, Kp, Vp, out);
}

// Round 11
// 144.788 us; speedup vs baseline: 1.9904x; 1.0436x over previous
//
#include <hip/hip_runtime.h>

#define B_DIM 8
#define T_DIM 2048
#define C_DIM 1024
#define H_DIM 128

typedef __attribute__((ext_vector_type(8))) short bf16x8;
typedef __attribute__((ext_vector_type(4))) float f32x4;

__device__ __forceinline__ short f2bf(float f) {
  union { float f; unsigned u; } v; v.f = f;
  unsigned u = v.u;
  unsigned r = (u + 0x7FFFu + ((u >> 16) & 1u)) >> 16;
  return (short)r;
}

// DPP rotate-reduce over the 16-lane row (n = lane&15), VALU-speed.
__device__ __forceinline__ float rowmax16(float x) {
  union { float f; int i; } a, t;
  a.f = x;
  t.i = __builtin_amdgcn_update_dpp(a.i, a.i, 0x128, 0xf, 0xf, false);  // ror:8
  a.f = fmaxf(a.f, t.f);
  t.i = __builtin_amdgcn_update_dpp(a.i, a.i, 0x124, 0xf, 0xf, false);  // ror:4
  a.f = fmaxf(a.f, t.f);
  t.i = __builtin_amdgcn_update_dpp(a.i, a.i, 0x122, 0xf, 0xf, false);  // ror:2
  a.f = fmaxf(a.f, t.f);
  t.i = __builtin_amdgcn_update_dpp(a.i, a.i, 0x121, 0xf, 0xf, false);  // ror:1
  a.f = fmaxf(a.f, t.f);
  return a.f;
}
__device__ __forceinline__ float rowsum16(float x) {
  union { float f; int i; } a, t;
  a.f = x;
  t.i = __builtin_amdgcn_update_dpp(a.i, a.i, 0x128, 0xf, 0xf, false);
  a.f += t.f;
  t.i = __builtin_amdgcn_update_dpp(a.i, a.i, 0x124, 0xf, 0xf, false);
  a.f += t.f;
  t.i = __builtin_amdgcn_update_dpp(a.i, a.i, 0x122, 0xf, 0xf, false);
  a.f += t.f;
  t.i = __builtin_amdgcn_update_dpp(a.i, a.i, 0x121, 0xf, 0xf, false);
  a.f += t.f;
  return a.f;
}

// ---------------------------------------------------------------------------
// Kernel 1: weight prep (1.5 MB) -> MFMA-FRAGMENT-PACKED Wtp (r9-verified).
// ---------------------------------------------------------------------------
#define NWE ((3 * C_DIM * H_DIM) / 8)       // 49152 items

__global__ __launch_bounds__(256) void wprep_kernel(
    const float* __restrict__ Wk, const float* __restrict__ Wq,
    const float* __restrict__ Wv, short* __restrict__ Wtp) {
  int j = blockIdx.x * 256 + threadIdx.x;
  if (j >= NWE) return;
  int w = j >> 14;             // 16384 items per weight
  int r = j & 16383;
  int h = r >> 7;              // C/8 = 128 items per h
  int c0 = (r & 127) * 8;
  const float* W = (w == 0) ? Wk : ((w == 1) ? Wq : Wv);
  __attribute__((aligned(16))) short t[8];
#pragma unroll
  for (int i = 0; i < 8; i++) t[i] = f2bf(W[(size_t)(c0 + i) * H_DIM + h]);
  int colg = w * 128 + h;
  int nt = colg >> 4, nn = colg & 15;
  int kc = c0 >> 5, quad = (c0 >> 3) & 3;
  *(int4*)(Wtp + ((size_t)(nt * 32 + kc) * 64 + quad * 16 + nn) * 8) =
      *(const int4*)t;
}

// ---------------------------------------------------------------------------
// Kernel 2: fused projection v6 — BARRIER-FREE K-loop.
// r9's loop kept __syncthreads per iter, and __syncthreads drains vmcnt(0):
// the 6 B-loads of iter t could never stay in flight into t+1 (VGPR=44,
// MfmaUtil 11%, nothing busy).  Fix: the whole 32-row A-tile is only 66KB --
// stage it ONCE (coalesced float4 -> f2bf -> conflict-free ds_write), one
// barrier, then 16 iterations of {6 B L2-frag loads + 4 A ds_reads + 12
// MFMA} with NO barriers: compiler pipelines loads across the entire K-loop.
// Pitch 1056 shorts == 16 words mod 32 -> m97's verified 8-phase A-read
// pattern.  66KB LDS -> 2 blocks/CU -> 16 waves/CU TLP.
// ---------------------------------------------------------------------------
__global__ __launch_bounds__(512, 2) void projf_kernel(
    const float* __restrict__ x, const short* __restrict__ Wtp,
    short* __restrict__ Kp, short* __restrict__ Qb, short* __restrict__ Vp) {
  const int m0 = blockIdx.x * 32;
  __shared__ short As[32][1056];      // 66 KB, full K staged once
  const int tid  = threadIdx.x;
  const int lane = tid & 63;
  const int wv   = tid >> 6;
  const int n    = lane & 15;
  const int quad = lane >> 4;

  // ---- stage A: 4096 8-float chunks; chunk = tid + k*512 (coalesced) ----
  {
    float4 xs[16];
#pragma unroll
    for (int k = 0; k < 8; k++) {
      int c = tid + k * 512;
      const float* src = x + (size_t)(m0 + (c >> 7)) * C_DIM + (c & 127) * 8;
      xs[k * 2]     = *(const float4*)src;
      xs[k * 2 + 1] = *(const float4*)(src + 4);
    }
#pragma unroll
    for (int k = 0; k < 8; k++) {
      int c = tid + k * 512;
      __attribute__((aligned(16))) short t8[8];
      t8[0] = f2bf(xs[k * 2].x);     t8[1] = f2bf(xs[k * 2].y);
      t8[2] = f2bf(xs[k * 2].z);     t8[3] = f2bf(xs[k * 2].w);
      t8[4] = f2bf(xs[k * 2 + 1].x); t8[5] = f2bf(xs[k * 2 + 1].y);
      t8[6] = f2bf(xs[k * 2 + 1].z); t8[7] = f2bf(xs[k * 2 + 1].w);
      *(int4*)&As[c >> 7][(c & 127) * 8] = *(const int4*)t8;
    }
  }
  __syncthreads();     // the ONLY barrier

  // per-wave B fragment base (lane*16B within each 1KB fragment)
  const short* Bw = Wtp + (size_t)(wv * 3) * 32 * 512 + lane * 8;

  f32x4 acc[2][3];
#pragma unroll
  for (int i = 0; i < 2; i++)
#pragma unroll
    for (int j = 0; j < 3; j++) {
      f32x4 z = {0.f, 0.f, 0.f, 0.f};
      acc[i][j] = z;
    }

#pragma unroll 4
  for (int it = 0; it < 16; ++it) {
    bf16x8 bF[6], aF[4];
#pragma unroll
    for (int ntl = 0; ntl < 3; ntl++)
#pragma unroll
      for (int kk = 0; kk < 2; kk++)
        bF[ntl * 2 + kk] =
            *(const bf16x8*)(Bw + (size_t)(ntl * 32 + it * 2 + kk) * 512);
#pragma unroll
    for (int mt = 0; mt < 2; mt++)
#pragma unroll
      for (int kk = 0; kk < 2; kk++)
        aF[mt * 2 + kk] =
            *(const bf16x8*)&As[mt * 16 + n][it * 64 + kk * 32 + quad * 8];
#pragma unroll
    for (int mt = 0; mt < 2; mt++)
#pragma unroll
      for (int ntl = 0; ntl < 3; ntl++)
#pragma unroll
        for (int kk = 0; kk < 2; kk++)
          acc[mt][ntl] = __builtin_amdgcn_mfma_f32_16x16x32_bf16(
              aF[mt * 2 + kk], bF[ntl * 2 + kk], acc[mt][ntl], 0, 0, 0);
  }

  // epilogue (verified r5-r9 math): C/D layout col = lane&15, row = quad*4+reg
#pragma unroll
  for (int mt = 0; mt < 2; mt++) {
#pragma unroll
    for (int ntl = 0; ntl < 3; ntl++) {
#pragma unroll
      for (int i = 0; i < 4; i++) {
        int row = m0 + mt * 16 + quad * 4 + i;   // global token index
        int col = wv * 48 + ntl * 16 + n;        // 0..383
        short v = f2bf(acc[mt][ntl][i]);
        int w = col >> 7;
        int c = col & 127;          // h index
        int bb = row >> 11;
        int t  = row & (T_DIM - 1);
        int tt = t >> 6;
        if (w == 0) {
          int rr = t & 63;
          int knt = rr >> 4, kn = rr & 15;
          int kc = c >> 5, kq = (c >> 3) & 3, kj = c & 7;
          Kp[(((size_t)(bb * 32 + tt) * 16 + knt * 4 + kc) * 512) +
             (kq * 16 + kn) * 8 + kj] = v;
        } else if (w == 1) {
          Qb[(size_t)row * H_DIM + c] = v;
        } else {
          int vkc = (t >> 5) & 1, vq = (t >> 3) & 3, vj = t & 7;
          int ht = c >> 4, vn = c & 15;
          Vp[(((size_t)(bb * 32 + tt) * 16 + ht * 2 + vkc) * 512) +
             (vq * 16 + vn) * 8 + vj] = v;
        }
      }
    }
  }
}

// ---------------------------------------------------------------------------
// Kernel 3: causal flash attention — unchanged (r6/r9-verified; ~46us).
// Barrier-free main loop; fragment-packed K/V 1KB loads; DPP softmax;
// LPT heavy-first; (256,2) keeps VGPR unclamped.
// ---------------------------------------------------------------------------
__global__ __launch_bounds__(256, 2) void attn_kernel(
    const short* __restrict__ Qb, const short* __restrict__ Kp,
    const short* __restrict__ Vp, float* __restrict__ out) {
  const int id = blockIdx.y * 128 + blockIdx.x;
  const int b  = id & 7;             // batch -> XCD spread
  const int qt = 127 - (id >> 3);    // heavy-first (LPT)
  const int q0 = qt * 16;
  const int tid  = threadIdx.x;
  const int lane = tid & 63;
  const int g    = tid >> 6;   // kv phase 0..3
  const int n    = lane & 15;
  const int quad = lane >> 4;

  __shared__ short Ps[4][16][72];   // per-wave P strips (9.2KB)
  __shared__ float Om[16][128];     // merge buffer (8KB)
  __shared__ float Ml[16][2];

  const int ntiles = (qt >> 2) + 1;
  const float scale = 0.08838834764831845f;  // 1/sqrt(128)
  const int row0 = q0 + quad * 4;            // + reg i

  const short* Kbase = Kp + (size_t)b * 32 * 16 * 512;
  const short* Vbase = Vp + (size_t)b * 32 * 16 * 512;

  // Q A-frags (same for all 4 waves)
  bf16x8 aQ[4];
  {
    const short* qrow = Qb + (size_t)(b * T_DIM + q0 + n) * H_DIM;
#pragma unroll
    for (int kc = 0; kc < 4; kc++)
      aQ[kc] = *(const bf16x8*)(qrow + kc * 32 + quad * 8);
  }

  f32x4 accO[8];
#pragma unroll
  for (int i = 0; i < 8; i++) {
    f32x4 z = {0.f, 0.f, 0.f, 0.f};
    accO[i] = z;
  }
  float mrow[4] = {-1e30f, -1e30f, -1e30f, -1e30f};
  float lrow[4] = {0.f, 0.f, 0.f, 0.f};

  for (int t = g; t < ntiles; t += 4) {
    const int j0 = t * 64;
    const short* Kt = Kbase + (size_t)t * 16 * 512 + lane * 8;
    const short* Vt = Vbase + (size_t)t * 16 * 512 + lane * 8;
    f32x4 accS[4];
#pragma unroll
    for (int nt = 0; nt < 4; nt++) {
      f32x4 z = {0.f, 0.f, 0.f, 0.f};
      accS[nt] = z;
    }
    // ---- K: all 16 coalesced 1KB loads in flight, then 16 MFMAs ----
    bf16x8 fr[16];
#pragma unroll
    for (int nt = 0; nt < 4; nt++)
#pragma unroll
      for (int kc = 0; kc < 4; kc++)
        fr[nt * 4 + kc] = *(const bf16x8*)(Kt + (nt * 4 + kc) * 512);
    __builtin_amdgcn_sched_barrier(0);
#pragma unroll
    for (int nt = 0; nt < 4; nt++)
#pragma unroll
      for (int kc = 0; kc < 4; kc++)
        accS[nt] = __builtin_amdgcn_mfma_f32_16x16x32_bf16(
            aQ[kc], fr[nt * 4 + kc], accS[nt], 0, 0, 0);
    __builtin_amdgcn_sched_barrier(0);

    // ---- scale + causal mask + row max (DPP) ----
    float mt4[4] = {-1e30f, -1e30f, -1e30f, -1e30f};
#pragma unroll
    for (int nt = 0; nt < 4; nt++) {
      int col = j0 + nt * 16 + n;
#pragma unroll
      for (int i = 0; i < 4; i++) {
        float s = accS[nt][i] * scale;
        s = (col > row0 + i) ? -1e30f : s;
        accS[nt][i] = s;
        mt4[i] = fmaxf(mt4[i], s);
      }
    }
#pragma unroll
    for (int i = 0; i < 4; i++) mt4[i] = rowmax16(mt4[i]);

    // ---- V batch 0 prefetch under softmax ----
    bf16x8 frv[8];
#pragma unroll
    for (int ht = 0; ht < 4; ht++)
#pragma unroll
      for (int kc = 0; kc < 2; kc++)
        frv[ht * 2 + kc] = *(const bf16x8*)(Vt + (ht * 2 + kc) * 512);
    __builtin_amdgcn_sched_barrier(0);

    // ---- softmax ----
    float alpha[4], rsum[4];
#pragma unroll
    for (int i = 0; i < 4; i++) {
      float mnew = fmaxf(mrow[i], mt4[i]);
      alpha[i] = __expf(mrow[i] - mnew);
      mrow[i] = mnew;
      rsum[i] = 0.f;
    }
#pragma unroll
    for (int nt = 0; nt < 4; nt++)
#pragma unroll
      for (int i = 0; i < 4; i++) {
        float p = __expf(accS[nt][i] - mrow[i]);
        rsum[i] += p;
        Ps[g][quad * 4 + i][nt * 16 + n] = f2bf(p);
      }
#pragma unroll
    for (int i = 0; i < 4; i++) {
      rsum[i] = rowsum16(rsum[i]);
      lrow[i] = lrow[i] * alpha[i] + rsum[i];
    }
#pragma unroll
    for (int ht = 0; ht < 8; ht++)
#pragma unroll
      for (int i = 0; i < 4; i++)
        accO[ht][i] *= alpha[i];

    // P strip written+read by the SAME wave: lgkmcnt wait suffices (rule 18)
    asm volatile("s_waitcnt lgkmcnt(0)" ::: "memory");
    __builtin_amdgcn_sched_barrier(0);

    bf16x8 aP[2];
#pragma unroll
    for (int kc = 0; kc < 2; kc++)
      aP[kc] = *(const bf16x8*)&Ps[g][n][kc * 32 + quad * 8];

    // ---- PV batch 0 (ht 0..3) ----
#pragma unroll
    for (int ht = 0; ht < 4; ht++)
#pragma unroll
      for (int kc = 0; kc < 2; kc++)
        accO[ht] = __builtin_amdgcn_mfma_f32_16x16x32_bf16(
            aP[kc], frv[ht * 2 + kc], accO[ht], 0, 0, 0);
    __builtin_amdgcn_sched_barrier(0);
    // ---- V batch 1 (ht 4..7) ----
#pragma unroll
    for (int ht = 0; ht < 4; ht++)
#pragma unroll
      for (int kc = 0; kc < 2; kc++)
        frv[ht * 2 + kc] = *(const bf16x8*)(Vt + ((ht + 4) * 2 + kc) * 512);
    __builtin_amdgcn_sched_barrier(0);
#pragma unroll
    for (int ht = 0; ht < 4; ht++)
#pragma unroll
      for (int kc = 0; kc < 2; kc++)
        accO[ht + 4] = __builtin_amdgcn_mfma_f32_16x16x32_bf16(
            aP[kc], frv[ht * 2 + kc], accO[ht + 4], 0, 0, 0);
  }

  // ---- merge the 4 kv-phase partials ----
  __syncthreads();
  if (g == 0) {
#pragma unroll
    for (int i = 0; i < 4; i++) {
      int r = quad * 4 + i;
#pragma unroll
      for (int ht = 0; ht < 8; ht++)
        Om[r][ht * 16 + n] = accO[ht][i];
      if (n == 0) { Ml[r][0] = mrow[i]; Ml[r][1] = lrow[i]; }
    }
  }
#pragma unroll
  for (int gg = 1; gg < 4; gg++) {
    __syncthreads();
    if (g == gg) {
#pragma unroll
      for (int i = 0; i < 4; i++) {
        int r = quad * 4 + i;
        float m1 = Ml[r][0], l1 = Ml[r][1];
        float mnew = fmaxf(mrow[i], m1);
        float a0 = __expf(mrow[i] - mnew);   // 0 when this phase had no tiles
        float a1 = __expf(m1 - mnew);
        float lnew = lrow[i] * a0 + l1 * a1;
        if (gg < 3) {
          if (n == 0) { Ml[r][0] = mnew; Ml[r][1] = lnew; }
#pragma unroll
          for (int ht = 0; ht < 8; ht++)
            Om[r][ht * 16 + n] = accO[ht][i] * a0 + Om[r][ht * 16 + n] * a1;
        } else {
          float linv = 1.0f / lnew;
          size_t base = (size_t)(b * T_DIM + q0 + r) * H_DIM;
#pragma unroll
          for (int ht = 0; ht < 8; ht++)
            out[base + ht * 16 + n] =
                (accO[ht][i] * a0 + Om[r][ht * 16 + n] * a1) * linv;
        }
      }
    }
  }
}

// ---------------------------------------------------------------------------
extern "C" void kernel_launch(void* const* d_in, const int* in_sizes, int n_in,
                              void* d_out, int out_size, void* d_ws, size_t ws_size,
                              hipStream_t stream) {
  (void)in_sizes; (void)n_in; (void)out_size; (void)ws_size;
  const float* x  = (const float*)d_in[0];
  const float* Wk = (const float*)d_in[1];
  const float* Wq = (const float*)d_in[2];
  const float* Wv = (const float*)d_in[3];
  float* out = (float*)d_out;

  char* ws = (char*)d_ws;
  short* Wtp = (short*)ws;                              // 786,432 B (frag-packed)
  short* Kp = (short*)(ws + 786432);                    // 4 MB (fragment-packed)
  short* Qb = (short*)(ws + 786432 + 4194304);          // 4 MB
  short* Vp = (short*)(ws + 786432 + 8388608);          // 4 MB (fragment-packed)

  wprep_kernel<<<dim3(192), dim3(256), 0, stream>>>(Wk, Wq, Wv, Wtp);
  projf_kernel<<<dim3(512), dim3(512), 0, stream>>>(x, Wtp, Kp, Qb, Vp);
  attn_kernel<<<dim3(128, 8), dim3(256), 0, stream>>>(Qb, Kp, Vp, out);
}